// Round 17
// baseline (342.328 us; speedup 1.0000x reference)
//
#include <hip/hip_runtime.h>
#include <hip/hip_bf16.h>
#include <cstdint>
#include <cstddef>

// ---------------------------------------------------------------------------
// Attention block: qkv = x @ wqkv^T ; rope(q,k) ; causal GQA attention ; out = att @ wo^T
// B=1, S=2048, DIM=4096, NH=32, NKV=8, HD=128. All compute in bf16 MFMA + f32 accum.
// RoPE is fused into gemm1's epilogue (f32, via shfl_xor(1) pair exchange).
// ---------------------------------------------------------------------------

typedef __attribute__((ext_vector_type(4)))  float    f32x4;
typedef __attribute__((ext_vector_type(16))) float    f32x16;
typedef __attribute__((ext_vector_type(8)))  __bf16   bf16x8;
typedef __attribute__((ext_vector_type(4)))  __bf16   bf16x4;
typedef __attribute__((ext_vector_type(2)))  __bf16   bf16x2;
typedef __attribute__((ext_vector_type(4)))  uint32_t u32x4;

typedef const __attribute__((address_space(1))) void* gaddr_t;
typedef __attribute__((address_space(3))) void*       laddr_t;

#define S_LEN   2048
#define DIM_    4096
#define NHEADS  32
#define NKV     8
#define HD      128
#define QKV_LD  6144   // row stride of qkv buffer (Q|K|V)
#define KOFF    4096
#define VOFF    5120

#define EXP2F(x) __builtin_amdgcn_exp2f(x)   // v_exp_f32 (2^x); __exp2f collides with glibc macro

// ---------------- fused f32 -> bf16 conversion (x, wqkv, wo in one pass) ---
#define N4_X  2097152   // 2048*4096/4
#define N4_W  6291456   // 6144*4096/4
#define N4_O  4194304   // 4096*4096/4
__global__ void cvt3(const float* __restrict__ x, __bf16* __restrict__ xb,
                     const float* __restrict__ wq, __bf16* __restrict__ wqb,
                     const float* __restrict__ wo, __bf16* __restrict__ wob) {
  int idx = blockIdx.x * blockDim.x + threadIdx.x;
  int stride = gridDim.x * blockDim.x;
  for (int i = idx; i < N4_X + N4_W + N4_O; i += stride) {
    const float* src; __bf16* dst; int k;
    if (i < N4_X)            { src = x;  dst = xb;  k = i; }
    else if (i < N4_X + N4_W){ src = wq; dst = wqb; k = i - N4_X; }
    else                     { src = wo; dst = wob; k = i - N4_X - N4_W; }
    float4 v = reinterpret_cast<const float4*>(src)[k];
    bf16x4 o;
    o[0] = (__bf16)v.x; o[1] = (__bf16)v.y; o[2] = (__bf16)v.z; o[3] = (__bf16)v.w;
    reinterpret_cast<bf16x4*>(dst)[k] = o;
  }
}

// ---------------- shared stage op: 64 rows x 128B, swizzled src ------------
__device__ __forceinline__ void stg64(const __bf16* __restrict__ P, int ld, int row0,
                                      int kt, char* dst, int tid) {
  int r = tid >> 3, g = tid & 7;
  int row = row0 + r;
  const __bf16* src = P + (size_t)row * ld + kt * 64 + ((g ^ (row & 7)) * 8);
  __builtin_amdgcn_global_load_lds((gaddr_t)src,
      (laddr_t)(dst + (tid & ~63) * 16), 16, 0, 0);
}

// ==================== gemm1: m201-faithful 8-phase, 256x256 ================
// (R15: verified; ~125 us. Loop untouched; R16 adds fused RoPE in epilogue.)
template <int QM, int QN, bool RA, bool RB, int VW>   // VW: -1 none, 4, 0
__device__ __forceinline__ void g1_phase(const __bf16* __restrict__ Ab,
                                         const __bf16* __restrict__ Bb,
                                         f32x4 (&acc)[8][4],
                                         bf16x8 (&afr)[4][2], bf16x8 (&bfr)[2][2],
                                         int wm, int wn, int l15, int hi, int tid,
                                         const __bf16* __restrict__ SP, int sld,
                                         int srow, int skt, char* sdst, bool doSt) {
  if constexpr (RA) {
#pragma unroll
    for (int fm = 0; fm < 4; ++fm) {
      int R = wm * 128 + QM * 64 + fm * 16 + l15;
#pragma unroll
      for (int kk = 0; kk < 2; ++kk)
        afr[fm][kk] = *reinterpret_cast<const bf16x8*>(
            (const char*)Ab + R * 128 + (((kk * 4 + hi) ^ (R & 7)) * 16));
    }
  }
  if constexpr (RB) {
#pragma unroll
    for (int fn = 0; fn < 2; ++fn) {
      int R = wn * 64 + QN * 32 + fn * 16 + l15;
#pragma unroll
      for (int kk = 0; kk < 2; ++kk)
        bfr[fn][kk] = *reinterpret_cast<const bf16x8*>(
            (const char*)Bb + R * 128 + (((kk * 4 + hi) ^ (R & 7)) * 16));
    }
  }
  if (doSt) {
    stg64(SP, sld, srow, skt, sdst, tid);
    stg64(SP, sld, srow + 64, skt, sdst + 8192, tid);
  }
  __builtin_amdgcn_s_barrier();
  asm volatile("s_waitcnt lgkmcnt(0)" ::: "memory");
  __builtin_amdgcn_sched_barrier(0);
  __builtin_amdgcn_s_setprio(1);
#pragma unroll
  for (int kk = 0; kk < 2; ++kk)
#pragma unroll
    for (int fm = 0; fm < 4; ++fm)
#pragma unroll
      for (int fn = 0; fn < 2; ++fn)
        acc[QM * 4 + fm][QN * 2 + fn] = __builtin_amdgcn_mfma_f32_16x16x32_bf16(
            afr[fm][kk], bfr[fn][kk], acc[QM * 4 + fm][QN * 2 + fn], 0, 0, 0);
  __builtin_amdgcn_s_setprio(0);
  if constexpr (VW == 4) asm volatile("s_waitcnt vmcnt(4)" ::: "memory");
  if constexpr (VW == 0) asm volatile("s_waitcnt vmcnt(0)" ::: "memory");
  __builtin_amdgcn_s_barrier();
}

// Grid: 192 blocks; xcd = bid&7, lid = bid>>3; m = lid%8, n = xcd*3 + lid/8.
__global__ __launch_bounds__(512) void g1_8p(const __bf16* __restrict__ A,
                                             const __bf16* __restrict__ B,
                                             __bf16* __restrict__ C,
                                             const float* __restrict__ fc,
                                             const float* __restrict__ fs,
                                             int K, int lda, int ldb, int ldc) {
  __shared__ __align__(16) __bf16 As[2][256 * 64];
  __shared__ __align__(16) __bf16 Bs[2][256 * 64];
  const int tid = threadIdx.x;
  const int l15 = tid & 15, hi = (tid >> 4) & 3, w = tid >> 6;
  const int wm = w >> 2, wn = w & 3;
  const int bid = blockIdx.x, xcd = bid & 7, lid = bid >> 3;
  const int m0 = (lid % 8) * 256;
  const int n0 = (xcd * 3 + lid / 8) * 256;

  f32x4 acc[8][4] = {};
  bf16x8 afr[4][2], bfr[2][2];
  char* A0 = (char*)As[0]; char* A1 = (char*)As[1];
  char* B0 = (char*)Bs[0]; char* B1 = (char*)Bs[1];

  // prologue (FIFO): t0 {A0,B0,A1,B1} -> buf0 ; t1 {A0, B1} -> buf1
  stg64(A, lda, m0,       0, A0,         tid); stg64(A, lda, m0 + 64,  0, A0 + 8192,  tid);
  stg64(B, ldb, n0,       0, B0,         tid); stg64(B, ldb, n0 + 64,  0, B0 + 8192,  tid);
  stg64(A, lda, m0 + 128, 0, A0 + 16384, tid); stg64(A, lda, m0 + 192, 0, A0 + 24576, tid);
  stg64(B, ldb, n0 + 128, 0, B0 + 16384, tid); stg64(B, ldb, n0 + 192, 0, B0 + 24576, tid);
  stg64(A, lda, m0,       1, A1,         tid); stg64(A, lda, m0 + 64,  1, A1 + 8192,  tid);
  stg64(B, ldb, n0 + 128, 1, B1 + 16384, tid); stg64(B, ldb, n0 + 192, 1, B1 + 24576, tid);
  asm volatile("s_waitcnt vmcnt(4)" ::: "memory");   // t0 fully landed; t1 A0,B1 in flight
  __builtin_amdgcn_s_barrier();

  const int nt = K >> 6;                  // 64 K-tiles
  for (int it = 0; it < nt; it += 2) {
    const bool sB = (it + 2 < nt), sC = (it + 3 < nt);
    const bool last = !sB;
    const __bf16* Ab0 = As[0]; const __bf16* Bb0 = Bs[0];
    const __bf16* Ab1 = As[1]; const __bf16* Bb1 = Bs[1];
    // phases 1-4: tile it (buf0)
    g1_phase<0, 0, true,  true, -1>(Ab0, Bb0, acc, afr, bfr, wm, wn, l15, hi, tid,
                                    A, lda, m0 + 128, it + 1, A1 + 16384, true);   // stage t+1:A1
    g1_phase<0, 1, false, true, -1>(Ab0, Bb0, acc, afr, bfr, wm, wn, l15, hi, tid,
                                    B, ldb, n0, it + 1, B1, true);                 // stage t+1:B0
    g1_phase<1, 1, true, false, -1>(Ab0, Bb0, acc, afr, bfr, wm, wn, l15, hi, tid,
                                    A, lda, m0, it + 2, A0, sB);                   // stage t+2:A0
    if (last)
      g1_phase<1, 0, false, true, 0>(Ab0, Bb0, acc, afr, bfr, wm, wn, l15, hi, tid,
                                     B, ldb, n0 + 128, it + 2, B0 + 16384, sB);    // vmcnt(0)
    else
      g1_phase<1, 0, false, true, 4>(Ab0, Bb0, acc, afr, bfr, wm, wn, l15, hi, tid,
                                     B, ldb, n0 + 128, it + 2, B0 + 16384, sB);    // stage t+2:B1
    // phases 5-8: tile it+1 (buf1)
    g1_phase<0, 0, true,  true, -1>(Ab1, Bb1, acc, afr, bfr, wm, wn, l15, hi, tid,
                                    A, lda, m0 + 128, it + 2, A0 + 16384, sB);     // stage t+2:A1
    g1_phase<0, 1, false, true, -1>(Ab1, Bb1, acc, afr, bfr, wm, wn, l15, hi, tid,
                                    B, ldb, n0, it + 2, B0, sB);                   // stage t+2:B0
    g1_phase<1, 1, true, false, -1>(Ab1, Bb1, acc, afr, bfr, wm, wn, l15, hi, tid,
                                    A, lda, m0, it + 3, A1, sC);                   // stage t+3:A0
    if (last)
      g1_phase<1, 0, false, true, 0>(Ab1, Bb1, acc, afr, bfr, wm, wn, l15, hi, tid,
                                     B, ldb, n0 + 128, it + 3, B1 + 16384, sC);
    else
      g1_phase<1, 0, false, true, 4>(Ab1, Bb1, acc, afr, bfr, wm, wn, l15, hi, tid,
                                     B, ldb, n0 + 128, it + 3, B1 + 16384, sC);    // stage t+3:B1
  }

  // ---- epilogue with fused RoPE (Q/K panels: col < 5120, block-uniform) ----
  // Pair (2i,2i+1) = lanes l, l^1 of same row; out = v*c -/+ p*sn (parity).
  const bool isqk = (n0 < VOFF);
  const float sgn = (l15 & 1) ? 1.f : -1.f;
#pragma unroll
  for (int qm = 0; qm < 2; ++qm)
#pragma unroll
    for (int fm = 0; fm < 4; ++fm)
#pragma unroll
      for (int qn = 0; qn < 2; ++qn)
#pragma unroll
        for (int fn = 0; fn < 2; ++fn) {
          int col = n0 + wn * 64 + qn * 32 + fn * 16 + l15;
          int fi = (col & 127) >> 1;
#pragma unroll
          for (int j = 0; j < 4; ++j) {
            int row = m0 + wm * 128 + qm * 64 + fm * 16 + hi * 4 + j;
            float v = acc[qm * 4 + fm][qn * 2 + fn][j];
            if (isqk) {
              float p = __shfl_xor(v, 1);
              float c = fc[row * 64 + fi], sn = fs[row * 64 + fi];
              v = v * c + sgn * p * sn;
            }
            C[(size_t)row * ldc + col] = (__bf16)v;
          }
        }
}

// ==================== gemm2: R8-proven 2-phase 32x32, 128x256 ==============
template <int MW, int NW, int KH, int NST, bool VM>
__device__ __forceinline__ void phase32(const __bf16* __restrict__ Ab,
                                        const __bf16* __restrict__ Bb,
                                        f32x16 (&acc)[MW][NW],
                                        int wm, int wn, int l31, int hi, int tid,
                                        const __bf16* __restrict__ SP, int sld,
                                        int srow0, char* sdst, int kt, bool st) {
  bf16x8 af[MW][2], bfr[NW][2];
#pragma unroll
  for (int mi = 0; mi < MW; ++mi) {
    int R = wm * (MW * 32) + mi * 32 + l31;
#pragma unroll
    for (int k2 = 0; k2 < 2; ++k2)
      af[mi][k2] = *reinterpret_cast<const bf16x8*>(
          (const char*)Ab + R * 128 + (((KH * 4 + k2 * 2 + hi) ^ (R & 7)) * 16));
  }
#pragma unroll
  for (int ni = 0; ni < NW; ++ni) {
    int R = wn * (NW * 32) + ni * 32 + l31;
#pragma unroll
    for (int k2 = 0; k2 < 2; ++k2)
      bfr[ni][k2] = *reinterpret_cast<const bf16x8*>(
          (const char*)Bb + R * 128 + (((KH * 4 + k2 * 2 + hi) ^ (R & 7)) * 16));
  }
  if (st) {
#pragma unroll
    for (int h = 0; h < NST; ++h)
      stg64(SP, sld, srow0 + h * 64, kt, sdst + h * 8192, tid);
  }
  __builtin_amdgcn_s_barrier();
  asm volatile("s_waitcnt lgkmcnt(0)" ::: "memory");
  __builtin_amdgcn_sched_barrier(0);
  __builtin_amdgcn_s_setprio(1);
#pragma unroll
  for (int k2 = 0; k2 < 2; ++k2)
#pragma unroll
    for (int mi = 0; mi < MW; ++mi)
#pragma unroll
      for (int ni = 0; ni < NW; ++ni)
        acc[mi][ni] = __builtin_amdgcn_mfma_f32_32x32x16_bf16(af[mi][k2], bfr[ni][k2],
                                                              acc[mi][ni], 0, 0, 0);
  __builtin_amdgcn_s_setprio(0);
  if (VM) asm volatile("s_waitcnt vmcnt(0)" ::: "memory");
  __builtin_amdgcn_s_barrier();
}

template <int BM, int BN, int MB, int NPX, typename OutT>
__global__ __launch_bounds__(512) void gemm32(const __bf16* __restrict__ A,
                                              const __bf16* __restrict__ B,
                                              OutT* __restrict__ C, int K,
                                              int lda, int ldb, int ldc) {
  constexpr int MW = BM / 64;
  constexpr int NW = BN / 128;
  constexpr int AST = BM / 64, BST = BN / 64;
  __shared__ __align__(16) __bf16 As[2][BM * 64];
  __shared__ __align__(16) __bf16 Bs[2][BN * 64];
  const int tid = threadIdx.x;
  const int lane = tid & 63, l31 = lane & 31, hi = lane >> 5, w = tid >> 6;
  const int wm = w >> 2, wn = w & 3;
  const int bid = blockIdx.x, xcd = bid & 7, lid = bid >> 3;
  const int m0 = (lid % MB) * BM;
  const int n0 = (xcd * NPX + lid / MB) * BN;

  f32x16 acc[MW][NW] = {};

#pragma unroll
  for (int h = 0; h < AST; ++h) stg64(A, lda, m0 + h * 64, 0, (char*)As[0] + h * 8192, tid);
#pragma unroll
  for (int h = 0; h < BST; ++h) stg64(B, ldb, n0 + h * 64, 0, (char*)Bs[0] + h * 8192, tid);
  asm volatile("s_waitcnt vmcnt(0)" ::: "memory");
  __builtin_amdgcn_s_barrier();

  const int ntiles = K >> 6;
  for (int t = 0; t < ntiles; ++t) {
    const int cur = t & 1;
    const __bf16* Ab = As[cur];
    const __bf16* Bb = Bs[cur];
    char* dA = (char*)As[1 - cur];
    char* dB = (char*)Bs[1 - cur];
    const bool st = (t + 1 < ntiles);
    phase32<MW, NW, 0, AST, false>(Ab, Bb, acc, wm, wn, l31, hi, tid,
                                   A, lda, m0, dA, t + 1, st);
    phase32<MW, NW, 1, BST, true >(Ab, Bb, acc, wm, wn, l31, hi, tid,
                                   B, ldb, n0, dB, t + 1, st);
  }

#pragma unroll
  for (int mi = 0; mi < MW; ++mi)
#pragma unroll
    for (int ni = 0; ni < NW; ++ni)
#pragma unroll
      for (int e = 0; e < 16; ++e) {
        int row = m0 + wm * (MW * 32) + mi * 32 + (e & 3) + 8 * (e >> 2) + 4 * hi;
        int col = n0 + wn * (NW * 32) + ni * 32 + l31;
        C[(size_t)row * ldc + col] = (OutT)acc[mi][ni][e];
      }
}

// ---------------- Flash attention, causal, GQA — staged K/V, 2 blocks/CU ---
// 512 blocks x 256 thr (4 waves x 32 q-rows, QBLK=128). V^T staging uses
// STATIC element indexing; bank spread via stride 66. Scale folded into exp2
// fma. setprio(1) around MFMA clusters (T5: blocks at 2/CU are phase-split).
__device__ inline uint32_t pack2(float a, float b) {
  bf16x2 t; t[0] = (__bf16)a; t[1] = (__bf16)b;
  return __builtin_bit_cast(uint32_t, t);
}

__global__ __launch_bounds__(256, 2) void attn_kernel(const __bf16* __restrict__ qkv,
                                                      __bf16* __restrict__ out) {
  __shared__ __align__(16) __bf16 Ks[2][64 * 128];   // XOR-swizzled 16B groups
  __shared__ __align__(16) __bf16 Vt[2][128][66];    // V^T, stride 132B
  const int tid = threadIdx.x;
  const int lane = tid & 63, l31 = lane & 31, hi = lane >> 5, wq = tid >> 6;
  const int head = blockIdx.x & 31;
  const int g = blockIdx.x >> 5;                     // 0..15
  const int qt = (g < 8) ? (15 - g) : (g - 8);       // LPT + slot pairing
  const int q0 = qt * 128;
  const int nt = 2 * qt + 2;                         // kv tiles (causal)
  const int kvh = head >> 2;
  const float sc2 = 0.08838834764831845f * 1.44269504089f;  // 1/sqrt(128)*log2(e)
  const int qr = q0 + wq * 32 + l31;                 // this lane's q row

  bf16x8 vr[2][2];  // in-flight V rows (2 tasks x 2 rows)

  auto stage_k = [&](int tt, int buf) {
#pragma unroll
    for (int i = 0; i < 4; ++i) {
      int c = i * 256 + tid;                         // 16B chunk 0..1023
      int r = c >> 4, gg = c & 15;
      const __bf16* gk = qkv + (size_t)(tt * 64 + r) * QKV_LD + KOFF + kvh * HD + ((gg ^ (r & 7)) * 8);
      __builtin_amdgcn_global_load_lds((gaddr_t)gk,
          (laddr_t)((char*)Ks[buf] + (tid & ~63) * 16 + i * 4096), 16, 0, 0);
    }
  };
  auto load_v = [&](int tt) {
#pragma unroll
    for (int i = 0; i < 2; ++i) {
      int task = i * 256 + tid;                      // 0..511
      int p = task >> 4, cg = task & 15;
      const __bf16* vp = qkv + (size_t)(tt * 64 + 2 * p) * QKV_LD + VOFF + kvh * HD + cg * 8;
      vr[i][0] = *reinterpret_cast<const bf16x8*>(vp);
      vr[i][1] = *reinterpret_cast<const bf16x8*>(vp + QKV_LD);
    }
  };
  auto write_v = [&](int buf) {
#pragma unroll
    for (int i = 0; i < 2; ++i) {
      int task = i * 256 + tid;
      int p = task >> 4, cg = task & 15;
#pragma unroll
      for (int e = 0; e < 8; ++e) {                  // STATIC index — no select trees
        bf16x2 pkv; pkv[0] = vr[i][0][e]; pkv[1] = vr[i][1][e];
        *reinterpret_cast<bf16x2*>(&Vt[buf][cg * 8 + e][2 * p]) = pkv;
      }
    }
  };

  // Q fragments (B-layout): lane holds Q[qr][k = ks*16 + hi*8 + 0..7]
  bf16x8 qf[8];
  {
    const __bf16* qp = qkv + (size_t)qr * QKV_LD + head * HD + hi * 8;
#pragma unroll
    for (int ks = 0; ks < 8; ++ks) qf[ks] = *reinterpret_cast<const bf16x8*>(qp + ks * 16);
  }
  f32x16 o[4] = {};
  float m_run = -3e38f, l_run = 0.f;

  stage_k(0, 0); load_v(0); write_v(0);

  for (int t = 0; t < nt; ++t) {
    const int cur = t & 1;
    __syncthreads();        // staging of buf[cur] visible; prev reads of buf[1-cur] done
    if (t + 1 < nt) { stage_k(t + 1, 1 - cur); load_v(t + 1); }

    // ---- S^T = K Q^T : col=q=l31, row=(e&3)+8*(e>>2)+4*hi  (RAW scores)
    f32x16 st[2];
    __builtin_amdgcn_s_setprio(1);
#pragma unroll
    for (int sub = 0; sub < 2; ++sub) {
      f32x16 acc = {};
      int r = sub * 32 + l31;
#pragma unroll
      for (int ks = 0; ks < 8; ++ks) {
        int gg = (ks * 2 + hi) ^ (r & 7);
        bf16x8 kf = *reinterpret_cast<const bf16x8*>((char*)Ks[cur] + r * 256 + gg * 16);
        acc = __builtin_amdgcn_mfma_f32_32x32x16_bf16(kf, qf[ks], acc, 0, 0, 0);
      }
      st[sub] = acc;
    }
    __builtin_amdgcn_s_setprio(0);
    if (t >= nt - 2) {      // only the two diagonal tiles need masking
      const int kv0 = t * 64;
#pragma unroll
      for (int sub = 0; sub < 2; ++sub)
#pragma unroll
        for (int e = 0; e < 16; ++e) {
          int kvg = kv0 + sub * 32 + (e & 3) + 8 * (e >> 2) + 4 * hi;
          if (kvg > qr) st[sub][e] = -1e30f;
        }
    }
    // ---- online softmax (lane-local, defer-max, scale folded into exp2 fma)
    float pm = st[0][0];
#pragma unroll
    for (int e = 1; e < 16; ++e) pm = fmaxf(pm, st[0][e]);
#pragma unroll
    for (int e = 0; e < 16; ++e) pm = fmaxf(pm, st[1][e]);
    pm = fmaxf(pm, __shfl_xor(pm, 32));
    pm *= sc2;                                       // to scaled domain
    if (!__all(pm - m_run <= 8.f)) {
      float mn = fmaxf(m_run, pm);
      float fsc = EXP2F(m_run - mn);
      m_run = mn;
      l_run *= fsc;
#pragma unroll
      for (int dt = 0; dt < 4; ++dt)
#pragma unroll
        for (int e = 0; e < 16; ++e) o[dt][e] *= fsc;
    }
    float rs = 0.f;
#pragma unroll
    for (int sub = 0; sub < 2; ++sub)
#pragma unroll
      for (int e = 0; e < 16; ++e) {
        float p = EXP2F(__builtin_fmaf(st[sub][e], sc2, -m_run));
        st[sub][e] = p;
        rs += p;
      }
    rs += __shfl_xor(rs, 32);
    l_run += rs;

    // ---- pack P to bf16 B-fragments: pf[tt] = P[qr][kv = tt*16 + hi*8 + 0..7]
    uint32_t pk[16];
#pragma unroll
    for (int sub = 0; sub < 2; ++sub)
#pragma unroll
      for (int i = 0; i < 8; ++i)
        pk[sub * 8 + i] = pack2(st[sub][2 * i], st[sub][2 * i + 1]);
    uint32_t rv[8];
#pragma unroll
    for (int m = 0; m < 8; ++m) {
      int base = 4 * (m >> 1) + (m & 1);
      uint32_t snd = hi ? pk[base] : pk[base + 2];
      rv[m] = __shfl_xor(snd, 32);
    }
    bf16x8 pf[4];
#pragma unroll
    for (int tt = 0; tt < 4; ++tt) {
      u32x4 wv;
      wv[0] = hi ? rv[2 * tt]     : pk[4 * tt];
      wv[1] = hi ? rv[2 * tt + 1] : pk[4 * tt + 1];
      wv[2] = hi ? pk[4 * tt + 2] : rv[2 * tt];
      wv[3] = hi ? pk[4 * tt + 3] : rv[2 * tt + 1];
      pf[tt] = __builtin_bit_cast(bf16x8, wv);
    }
    // ---- O^T += V^T P^T
    __builtin_amdgcn_s_setprio(1);
#pragma unroll
    for (int dt = 0; dt < 4; ++dt) {
      int dr = dt * 32 + l31;
#pragma unroll
      for (int tt = 0; tt < 4; ++tt) {
        bf16x8 vf = *reinterpret_cast<const bf16x8*>((char*)&Vt[cur][0][0] + dr * 132 + tt * 32 + hi * 16);
        o[dt] = __builtin_amdgcn_mfma_f32_32x32x16_bf16(vf, pf[tt], o[dt], 0, 0, 0);
      }
    }
    __builtin_amdgcn_s_setprio(0);
    // ---- late V^T write for next tile (loads had QK+softmax+PV to land)
    if (t + 1 < nt) write_v(1 - cur);
  }

  // ---- epilogue: transpose O^T -> O via per-wave LDS scratch, coalesced stores
  float inv = 1.f / l_run;
  __bf16* scr = &Ks[0][0] + wq * 1280;               // [32][40] bf16 per wave
  const int qq = lane >> 1, part = lane & 1;
#pragma unroll
  for (int dt = 0; dt < 4; ++dt) {
    __syncthreads();                                 // all waves done reading Ks/Vt (or prev dt)
#pragma unroll
    for (int i = 0; i < 8; ++i) {
      int d0 = (2 * i & 3) + 8 * (i >> 1) + 4 * hi;
      bf16x2 prr;
      prr[0] = (__bf16)(o[dt][2 * i] * inv);
      prr[1] = (__bf16)(o[dt][2 * i + 1] * inv);
      *reinterpret_cast<bf16x2*>(scr + l31 * 40 + d0) = prr;
    }
    __syncthreads();
    bf16x8 r0 = *reinterpret_cast<const bf16x8*>(scr + qq * 40 + part * 16);
    bf16x8 r1 = *reinterpret_cast<const bf16x8*>(scr + qq * 40 + part * 16 + 8);
    __bf16* op = out + (size_t)(q0 + wq * 32 + qq) * DIM_ + head * HD + dt * 32 + part * 16;
    *reinterpret_cast<bf16x8*>(op) = r0;
    *reinterpret_cast<bf16x8*>(op + 8) = r1;
  }
}

// ---------------------------------------------------------------------------
extern "C" void kernel_launch(void* const* d_in, const int* in_sizes, int n_in,
                              void* d_out, int out_size, void* d_ws, size_t ws_size,
                              hipStream_t stream) {
  (void)in_sizes; (void)n_in; (void)out_size; (void)ws_size;
  const float* x    = (const float*)d_in[0];
  const float* fc   = (const float*)d_in[1];
  const float* fs   = (const float*)d_in[2];
  // d_in[3] = mask (causal, hardcoded in attn_kernel)
  const float* wqkv = (const float*)d_in[4];
  const float* wo   = (const float*)d_in[5];
  float* out = (float*)d_out;

  char* ws = (char*)d_ws;
  __bf16* xb    = (__bf16*)(ws);                       // 16,777,216  (reused as attn_out)
  __bf16* wqkvb = (__bf16*)(ws + 16777216);            // 50,331,648
  __bf16* wob   = (__bf16*)(ws + 67108864);            // 33,554,432
  __bf16* qkv   = (__bf16*)(ws + 100663296);           // 25,165,824
  __bf16* attnO = xb;                                  // xb dead after gemm1

  // single fused conversion pass (x, wqkv, wo)
  cvt3<<<2048, 256, 0, stream>>>(x, xb, wqkv, wqkvb, wo, wob);

  // qkv = x @ wqkv^T (+ fused RoPE on Q/K panels): 256x256 tiles, 192 blocks, 8-phase.
  g1_8p<<<192, 512, 0, stream>>>(xb, wqkvb, qkv, fc, fs, DIM_, DIM_, DIM_, QKV_LD);

  // causal GQA attention (512 blocks x 256 threads, 2 blocks/CU, paired LPT)
  attn_kernel<<<512, 256, 0, stream>>>(qkv, attnO);

  // out = attnO @ wo^T : M=2048, N=4096, K=4096. 128x256 tiles -> 256 blocks, 2-phase.
  gemm32<128, 256, 16, 2, float><<<256, 512, 0, stream>>>(attnO, wob, out, DIM_, DIM_, DIM_, DIM_);
}

// Round 18
// 326.340 us; speedup vs baseline: 1.0490x; 1.0490x over previous
//
#include <hip/hip_runtime.h>
#include <hip/hip_bf16.h>
#include <cstdint>
#include <cstddef>

// ---------------------------------------------------------------------------
// Attention block: qkv = x @ wqkv^T ; rope(q,k) ; causal GQA attention ; out = att @ wo^T
// B=1, S=2048, DIM=4096, NH=32, NKV=8, HD=128. All compute in bf16 MFMA + f32 accum.
// R17 lesson: RoPE fused into gemm1 epilogue costs +45us (shfl/bpermute + f32
// table gathers in the MFMA kernel's tail) — standalone rope pass is cheaper.
// ---------------------------------------------------------------------------

typedef __attribute__((ext_vector_type(4)))  float    f32x4;
typedef __attribute__((ext_vector_type(16))) float    f32x16;
typedef __attribute__((ext_vector_type(8)))  __bf16   bf16x8;
typedef __attribute__((ext_vector_type(4)))  __bf16   bf16x4;
typedef __attribute__((ext_vector_type(2)))  __bf16   bf16x2;
typedef __attribute__((ext_vector_type(4)))  uint32_t u32x4;

typedef const __attribute__((address_space(1))) void* gaddr_t;
typedef __attribute__((address_space(3))) void*       laddr_t;

#define S_LEN   2048
#define DIM_    4096
#define NHEADS  32
#define NKV     8
#define HD      128
#define QKV_LD  6144   // row stride of qkv buffer (Q|K|V)
#define KOFF    4096
#define VOFF    5120

#define EXP2F(x) __builtin_amdgcn_exp2f(x)   // v_exp_f32 (2^x); __exp2f collides with glibc macro

// ---------------- fused f32 -> bf16 conversion (x, wqkv, wo in one pass) ---
#define N4_X  2097152   // 2048*4096/4
#define N4_W  6291456   // 6144*4096/4
#define N4_O  4194304   // 4096*4096/4
__global__ void cvt3(const float* __restrict__ x, __bf16* __restrict__ xb,
                     const float* __restrict__ wq, __bf16* __restrict__ wqb,
                     const float* __restrict__ wo, __bf16* __restrict__ wob) {
  int idx = blockIdx.x * blockDim.x + threadIdx.x;
  int stride = gridDim.x * blockDim.x;
  for (int i = idx; i < N4_X + N4_W + N4_O; i += stride) {
    const float* src; __bf16* dst; int k;
    if (i < N4_X)            { src = x;  dst = xb;  k = i; }
    else if (i < N4_X + N4_W){ src = wq; dst = wqb; k = i - N4_X; }
    else                     { src = wo; dst = wob; k = i - N4_X - N4_W; }
    float4 v = reinterpret_cast<const float4*>(src)[k];
    bf16x4 o;
    o[0] = (__bf16)v.x; o[1] = (__bf16)v.y; o[2] = (__bf16)v.z; o[3] = (__bf16)v.w;
    reinterpret_cast<bf16x4*>(dst)[k] = o;
  }
}

// ---------------- RoPE in-place on Q and K parts of qkv --------------------
__global__ void rope_kernel(__bf16* __restrict__ qkv, const float* __restrict__ fc,
                            const float* __restrict__ fs) {
  int tid = blockIdx.x * 256 + threadIdx.x;   // 0 .. 2048*40*64-1
  int i = tid & 63;
  int t = tid >> 6;
  int h = t % 40;
  int s = t / 40;
  int col = (h < NHEADS) ? (h * HD + 2 * i) : (KOFF + (h - NHEADS) * HD + 2 * i);
  size_t off = (size_t)s * QKV_LD + col;
  float c = fc[s * 64 + i], sn = fs[s * 64 + i];
  bf16x2 v = *reinterpret_cast<bf16x2*>(&qkv[off]);
  float t0 = (float)v[0], t1 = (float)v[1];
  bf16x2 o;
  o[0] = (__bf16)(t0 * c - t1 * sn);
  o[1] = (__bf16)(t0 * sn + t1 * c);
  *reinterpret_cast<bf16x2*>(&qkv[off]) = o;
}

// ---------------- shared stage op: 64 rows x 128B, swizzled src ------------
__device__ __forceinline__ void stg64(const __bf16* __restrict__ P, int ld, int row0,
                                      int kt, char* dst, int tid) {
  int r = tid >> 3, g = tid & 7;
  int row = row0 + r;
  const __bf16* src = P + (size_t)row * ld + kt * 64 + ((g ^ (row & 7)) * 8);
  __builtin_amdgcn_global_load_lds((gaddr_t)src,
      (laddr_t)(dst + (tid & ~63) * 16), 16, 0, 0);
}

// ==================== gemm1: m201-faithful 8-phase, 256x256 ================
// (R15: verified; ~125 us, MfmaUtil 34%. DO NOT TOUCH — R17's epilogue-RoPE
// fusion cost +45us and was reverted.)
template <int QM, int QN, bool RA, bool RB, int VW>   // VW: -1 none, 4, 0
__device__ __forceinline__ void g1_phase(const __bf16* __restrict__ Ab,
                                         const __bf16* __restrict__ Bb,
                                         f32x4 (&acc)[8][4],
                                         bf16x8 (&afr)[4][2], bf16x8 (&bfr)[2][2],
                                         int wm, int wn, int l15, int hi, int tid,
                                         const __bf16* __restrict__ SP, int sld,
                                         int srow, int skt, char* sdst, bool doSt) {
  if constexpr (RA) {
#pragma unroll
    for (int fm = 0; fm < 4; ++fm) {
      int R = wm * 128 + QM * 64 + fm * 16 + l15;
#pragma unroll
      for (int kk = 0; kk < 2; ++kk)
        afr[fm][kk] = *reinterpret_cast<const bf16x8*>(
            (const char*)Ab + R * 128 + (((kk * 4 + hi) ^ (R & 7)) * 16));
    }
  }
  if constexpr (RB) {
#pragma unroll
    for (int fn = 0; fn < 2; ++fn) {
      int R = wn * 64 + QN * 32 + fn * 16 + l15;
#pragma unroll
      for (int kk = 0; kk < 2; ++kk)
        bfr[fn][kk] = *reinterpret_cast<const bf16x8*>(
            (const char*)Bb + R * 128 + (((kk * 4 + hi) ^ (R & 7)) * 16));
    }
  }
  if (doSt) {
    stg64(SP, sld, srow, skt, sdst, tid);
    stg64(SP, sld, srow + 64, skt, sdst + 8192, tid);
  }
  __builtin_amdgcn_s_barrier();
  asm volatile("s_waitcnt lgkmcnt(0)" ::: "memory");
  __builtin_amdgcn_sched_barrier(0);
  __builtin_amdgcn_s_setprio(1);
#pragma unroll
  for (int kk = 0; kk < 2; ++kk)
#pragma unroll
    for (int fm = 0; fm < 4; ++fm)
#pragma unroll
      for (int fn = 0; fn < 2; ++fn)
        acc[QM * 4 + fm][QN * 2 + fn] = __builtin_amdgcn_mfma_f32_16x16x32_bf16(
            afr[fm][kk], bfr[fn][kk], acc[QM * 4 + fm][QN * 2 + fn], 0, 0, 0);
  __builtin_amdgcn_s_setprio(0);
  if constexpr (VW == 4) asm volatile("s_waitcnt vmcnt(4)" ::: "memory");
  if constexpr (VW == 0) asm volatile("s_waitcnt vmcnt(0)" ::: "memory");
  __builtin_amdgcn_s_barrier();
}

// Grid: 192 blocks; xcd = bid&7, lid = bid>>3; m = lid%8, n = xcd*3 + lid/8.
__global__ __launch_bounds__(512) void g1_8p(const __bf16* __restrict__ A,
                                             const __bf16* __restrict__ B,
                                             __bf16* __restrict__ C, int K,
                                             int lda, int ldb, int ldc) {
  __shared__ __align__(16) __bf16 As[2][256 * 64];
  __shared__ __align__(16) __bf16 Bs[2][256 * 64];
  const int tid = threadIdx.x;
  const int l15 = tid & 15, hi = (tid >> 4) & 3, w = tid >> 6;
  const int wm = w >> 2, wn = w & 3;
  const int bid = blockIdx.x, xcd = bid & 7, lid = bid >> 3;
  const int m0 = (lid % 8) * 256;
  const int n0 = (xcd * 3 + lid / 8) * 256;

  f32x4 acc[8][4] = {};
  bf16x8 afr[4][2], bfr[2][2];
  char* A0 = (char*)As[0]; char* A1 = (char*)As[1];
  char* B0 = (char*)Bs[0]; char* B1 = (char*)Bs[1];

  // prologue (FIFO): t0 {A0,B0,A1,B1} -> buf0 ; t1 {A0, B1} -> buf1
  stg64(A, lda, m0,       0, A0,         tid); stg64(A, lda, m0 + 64,  0, A0 + 8192,  tid);
  stg64(B, ldb, n0,       0, B0,         tid); stg64(B, ldb, n0 + 64,  0, B0 + 8192,  tid);
  stg64(A, lda, m0 + 128, 0, A0 + 16384, tid); stg64(A, lda, m0 + 192, 0, A0 + 24576, tid);
  stg64(B, ldb, n0 + 128, 0, B0 + 16384, tid); stg64(B, ldb, n0 + 192, 0, B0 + 24576, tid);
  stg64(A, lda, m0,       1, A1,         tid); stg64(A, lda, m0 + 64,  1, A1 + 8192,  tid);
  stg64(B, ldb, n0 + 128, 1, B1 + 16384, tid); stg64(B, ldb, n0 + 192, 1, B1 + 24576, tid);
  asm volatile("s_waitcnt vmcnt(4)" ::: "memory");   // t0 fully landed; t1 A0,B1 in flight
  __builtin_amdgcn_s_barrier();

  const int nt = K >> 6;                  // 64 K-tiles
  for (int it = 0; it < nt; it += 2) {
    const bool sB = (it + 2 < nt), sC = (it + 3 < nt);
    const bool last = !sB;
    const __bf16* Ab0 = As[0]; const __bf16* Bb0 = Bs[0];
    const __bf16* Ab1 = As[1]; const __bf16* Bb1 = Bs[1];
    // phases 1-4: tile it (buf0)
    g1_phase<0, 0, true,  true, -1>(Ab0, Bb0, acc, afr, bfr, wm, wn, l15, hi, tid,
                                    A, lda, m0 + 128, it + 1, A1 + 16384, true);   // stage t+1:A1
    g1_phase<0, 1, false, true, -1>(Ab0, Bb0, acc, afr, bfr, wm, wn, l15, hi, tid,
                                    B, ldb, n0, it + 1, B1, true);                 // stage t+1:B0
    g1_phase<1, 1, true, false, -1>(Ab0, Bb0, acc, afr, bfr, wm, wn, l15, hi, tid,
                                    A, lda, m0, it + 2, A0, sB);                   // stage t+2:A0
    if (last)
      g1_phase<1, 0, false, true, 0>(Ab0, Bb0, acc, afr, bfr, wm, wn, l15, hi, tid,
                                     B, ldb, n0 + 128, it + 2, B0 + 16384, sB);    // vmcnt(0)
    else
      g1_phase<1, 0, false, true, 4>(Ab0, Bb0, acc, afr, bfr, wm, wn, l15, hi, tid,
                                     B, ldb, n0 + 128, it + 2, B0 + 16384, sB);    // stage t+2:B1
    // phases 5-8: tile it+1 (buf1)
    g1_phase<0, 0, true,  true, -1>(Ab1, Bb1, acc, afr, bfr, wm, wn, l15, hi, tid,
                                    A, lda, m0 + 128, it + 2, A0 + 16384, sB);     // stage t+2:A1
    g1_phase<0, 1, false, true, -1>(Ab1, Bb1, acc, afr, bfr, wm, wn, l15, hi, tid,
                                    B, ldb, n0, it + 2, B0, sB);                   // stage t+2:B0
    g1_phase<1, 1, true, false, -1>(Ab1, Bb1, acc, afr, bfr, wm, wn, l15, hi, tid,
                                    A, lda, m0, it + 3, A1, sC);                   // stage t+3:A0
    if (last)
      g1_phase<1, 0, false, true, 0>(Ab1, Bb1, acc, afr, bfr, wm, wn, l15, hi, tid,
                                     B, ldb, n0 + 128, it + 3, B1 + 16384, sC);
    else
      g1_phase<1, 0, false, true, 4>(Ab1, Bb1, acc, afr, bfr, wm, wn, l15, hi, tid,
                                     B, ldb, n0 + 128, it + 3, B1 + 16384, sC);    // stage t+3:B1
  }

  // epilogue: 16x16 C layout — row = ... + hi*4 + j, col = ... + l15
#pragma unroll
  for (int qm = 0; qm < 2; ++qm)
#pragma unroll
    for (int fm = 0; fm < 4; ++fm)
#pragma unroll
      for (int qn = 0; qn < 2; ++qn)
#pragma unroll
        for (int fn = 0; fn < 2; ++fn)
#pragma unroll
          for (int j = 0; j < 4; ++j) {
            int row = m0 + wm * 128 + qm * 64 + fm * 16 + hi * 4 + j;
            int col = n0 + wn * 64 + qn * 32 + fn * 16 + l15;
            C[(size_t)row * ldc + col] = (__bf16)acc[qm * 4 + fm][qn * 2 + fn][j];
          }
}

// ==================== gemm2: R8-proven 2-phase 32x32, 128x256 ==============
template <int MW, int NW, int KH, int NST, bool VM>
__device__ __forceinline__ void phase32(const __bf16* __restrict__ Ab,
                                        const __bf16* __restrict__ Bb,
                                        f32x16 (&acc)[MW][NW],
                                        int wm, int wn, int l31, int hi, int tid,
                                        const __bf16* __restrict__ SP, int sld,
                                        int srow0, char* sdst, int kt, bool st) {
  bf16x8 af[MW][2], bfr[NW][2];
#pragma unroll
  for (int mi = 0; mi < MW; ++mi) {
    int R = wm * (MW * 32) + mi * 32 + l31;
#pragma unroll
    for (int k2 = 0; k2 < 2; ++k2)
      af[mi][k2] = *reinterpret_cast<const bf16x8*>(
          (const char*)Ab + R * 128 + (((KH * 4 + k2 * 2 + hi) ^ (R & 7)) * 16));
  }
#pragma unroll
  for (int ni = 0; ni < NW; ++ni) {
    int R = wn * (NW * 32) + ni * 32 + l31;
#pragma unroll
    for (int k2 = 0; k2 < 2; ++k2)
      bfr[ni][k2] = *reinterpret_cast<const bf16x8*>(
          (const char*)Bb + R * 128 + (((KH * 4 + k2 * 2 + hi) ^ (R & 7)) * 16));
  }
  if (st) {
#pragma unroll
    for (int h = 0; h < NST; ++h)
      stg64(SP, sld, srow0 + h * 64, kt, sdst + h * 8192, tid);
  }
  __builtin_amdgcn_s_barrier();
  asm volatile("s_waitcnt lgkmcnt(0)" ::: "memory");
  __builtin_amdgcn_sched_barrier(0);
  __builtin_amdgcn_s_setprio(1);
#pragma unroll
  for (int k2 = 0; k2 < 2; ++k2)
#pragma unroll
    for (int mi = 0; mi < MW; ++mi)
#pragma unroll
      for (int ni = 0; ni < NW; ++ni)
        acc[mi][ni] = __builtin_amdgcn_mfma_f32_32x32x16_bf16(af[mi][k2], bfr[ni][k2],
                                                              acc[mi][ni], 0, 0, 0);
  __builtin_amdgcn_s_setprio(0);
  if (VM) asm volatile("s_waitcnt vmcnt(0)" ::: "memory");
  __builtin_amdgcn_s_barrier();
}

template <int BM, int BN, int MB, int NPX, typename OutT>
__global__ __launch_bounds__(512) void gemm32(const __bf16* __restrict__ A,
                                              const __bf16* __restrict__ B,
                                              OutT* __restrict__ C, int K,
                                              int lda, int ldb, int ldc) {
  constexpr int MW = BM / 64;
  constexpr int NW = BN / 128;
  constexpr int AST = BM / 64, BST = BN / 64;
  __shared__ __align__(16) __bf16 As[2][BM * 64];
  __shared__ __align__(16) __bf16 Bs[2][BN * 64];
  const int tid = threadIdx.x;
  const int lane = tid & 63, l31 = lane & 31, hi = lane >> 5, w = tid >> 6;
  const int wm = w >> 2, wn = w & 3;
  const int bid = blockIdx.x, xcd = bid & 7, lid = bid >> 3;
  const int m0 = (lid % MB) * BM;
  const int n0 = (xcd * NPX + lid / MB) * BN;

  f32x16 acc[MW][NW] = {};

#pragma unroll
  for (int h = 0; h < AST; ++h) stg64(A, lda, m0 + h * 64, 0, (char*)As[0] + h * 8192, tid);
#pragma unroll
  for (int h = 0; h < BST; ++h) stg64(B, ldb, n0 + h * 64, 0, (char*)Bs[0] + h * 8192, tid);
  asm volatile("s_waitcnt vmcnt(0)" ::: "memory");
  __builtin_amdgcn_s_barrier();

  const int ntiles = K >> 6;
  for (int t = 0; t < ntiles; ++t) {
    const int cur = t & 1;
    const __bf16* Ab = As[cur];
    const __bf16* Bb = Bs[cur];
    char* dA = (char*)As[1 - cur];
    char* dB = (char*)Bs[1 - cur];
    const bool st = (t + 1 < ntiles);
    phase32<MW, NW, 0, AST, false>(Ab, Bb, acc, wm, wn, l31, hi, tid,
                                   A, lda, m0, dA, t + 1, st);
    phase32<MW, NW, 1, BST, true >(Ab, Bb, acc, wm, wn, l31, hi, tid,
                                   B, ldb, n0, dB, t + 1, st);
  }

#pragma unroll
  for (int mi = 0; mi < MW; ++mi)
#pragma unroll
    for (int ni = 0; ni < NW; ++ni)
#pragma unroll
      for (int e = 0; e < 16; ++e) {
        int row = m0 + wm * (MW * 32) + mi * 32 + (e & 3) + 8 * (e >> 2) + 4 * hi;
        int col = n0 + wn * (NW * 32) + ni * 32 + l31;
        C[(size_t)row * ldc + col] = (OutT)acc[mi][ni][e];
      }
}

// ---------------- Flash attention, causal, GQA — staged K/V, 2 blocks/CU ---
// 512 blocks x 256 thr (4 waves x 32 q-rows, QBLK=128). Static-index V^T
// staging (stride 66), scale folded into exp2 fma, setprio around MFMA.
__device__ inline uint32_t pack2(float a, float b) {
  bf16x2 t; t[0] = (__bf16)a; t[1] = (__bf16)b;
  return __builtin_bit_cast(uint32_t, t);
}

__global__ __launch_bounds__(256, 2) void attn_kernel(const __bf16* __restrict__ qkv,
                                                      __bf16* __restrict__ out) {
  __shared__ __align__(16) __bf16 Ks[2][64 * 128];   // XOR-swizzled 16B groups
  __shared__ __align__(16) __bf16 Vt[2][128][66];    // V^T, stride 132B
  const int tid = threadIdx.x;
  const int lane = tid & 63, l31 = lane & 31, hi = lane >> 5, wq = tid >> 6;
  const int head = blockIdx.x & 31;
  const int g = blockIdx.x >> 5;                     // 0..15
  const int qt = (g < 8) ? (15 - g) : (g - 8);       // LPT + slot pairing
  const int q0 = qt * 128;
  const int nt = 2 * qt + 2;                         // kv tiles (causal)
  const int kvh = head >> 2;
  const float sc2 = 0.08838834764831845f * 1.44269504089f;  // 1/sqrt(128)*log2(e)
  const int qr = q0 + wq * 32 + l31;                 // this lane's q row

  bf16x8 vr[2][2];  // in-flight V rows (2 tasks x 2 rows)

  auto stage_k = [&](int tt, int buf) {
#pragma unroll
    for (int i = 0; i < 4; ++i) {
      int c = i * 256 + tid;                         // 16B chunk 0..1023
      int r = c >> 4, gg = c & 15;
      const __bf16* gk = qkv + (size_t)(tt * 64 + r) * QKV_LD + KOFF + kvh * HD + ((gg ^ (r & 7)) * 8);
      __builtin_amdgcn_global_load_lds((gaddr_t)gk,
          (laddr_t)((char*)Ks[buf] + (tid & ~63) * 16 + i * 4096), 16, 0, 0);
    }
  };
  auto load_v = [&](int tt) {
#pragma unroll
    for (int i = 0; i < 2; ++i) {
      int task = i * 256 + tid;                      // 0..511
      int p = task >> 4, cg = task & 15;
      const __bf16* vp = qkv + (size_t)(tt * 64 + 2 * p) * QKV_LD + VOFF + kvh * HD + cg * 8;
      vr[i][0] = *reinterpret_cast<const bf16x8*>(vp);
      vr[i][1] = *reinterpret_cast<const bf16x8*>(vp + QKV_LD);
    }
  };
  auto write_v = [&](int buf) {
#pragma unroll
    for (int i = 0; i < 2; ++i) {
      int task = i * 256 + tid;
      int p = task >> 4, cg = task & 15;
#pragma unroll
      for (int e = 0; e < 8; ++e) {                  // STATIC index — no select trees
        bf16x2 pkv; pkv[0] = vr[i][0][e]; pkv[1] = vr[i][1][e];
        *reinterpret_cast<bf16x2*>(&Vt[buf][cg * 8 + e][2 * p]) = pkv;
      }
    }
  };

  // Q fragments (B-layout): lane holds Q[qr][k = ks*16 + hi*8 + 0..7]
  bf16x8 qf[8];
  {
    const __bf16* qp = qkv + (size_t)qr * QKV_LD + head * HD + hi * 8;
#pragma unroll
    for (int ks = 0; ks < 8; ++ks) qf[ks] = *reinterpret_cast<const bf16x8*>(qp + ks * 16);
  }
  f32x16 o[4] = {};
  float m_run = -3e38f, l_run = 0.f;

  stage_k(0, 0); load_v(0); write_v(0);

  for (int t = 0; t < nt; ++t) {
    const int cur = t & 1;
    __syncthreads();        // staging of buf[cur] visible; prev reads of buf[1-cur] done
    if (t + 1 < nt) { stage_k(t + 1, 1 - cur); load_v(t + 1); }

    // ---- S^T = K Q^T : col=q=l31, row=(e&3)+8*(e>>2)+4*hi  (RAW scores)
    f32x16 st[2];
    __builtin_amdgcn_s_setprio(1);
#pragma unroll
    for (int sub = 0; sub < 2; ++sub) {
      f32x16 acc = {};
      int r = sub * 32 + l31;
#pragma unroll
      for (int ks = 0; ks < 8; ++ks) {
        int gg = (ks * 2 + hi) ^ (r & 7);
        bf16x8 kf = *reinterpret_cast<const bf16x8*>((char*)Ks[cur] + r * 256 + gg * 16);
        acc = __builtin_amdgcn_mfma_f32_32x32x16_bf16(kf, qf[ks], acc, 0, 0, 0);
      }
      st[sub] = acc;
    }
    __builtin_amdgcn_s_setprio(0);
    if (t >= nt - 2) {      // only the two diagonal tiles need masking
      const int kv0 = t * 64;
#pragma unroll
      for (int sub = 0; sub < 2; ++sub)
#pragma unroll
        for (int e = 0; e < 16; ++e) {
          int kvg = kv0 + sub * 32 + (e & 3) + 8 * (e >> 2) + 4 * hi;
          if (kvg > qr) st[sub][e] = -1e30f;
        }
    }
    // ---- online softmax (lane-local, defer-max, scale folded into exp2 fma)
    float pm = st[0][0];
#pragma unroll
    for (int e = 1; e < 16; ++e) pm = fmaxf(pm, st[0][e]);
#pragma unroll
    for (int e = 0; e < 16; ++e) pm = fmaxf(pm, st[1][e]);
    pm = fmaxf(pm, __shfl_xor(pm, 32));
    pm *= sc2;                                       // to scaled domain
    if (!__all(pm - m_run <= 8.f)) {
      float mn = fmaxf(m_run, pm);
      float fsc = EXP2F(m_run - mn);
      m_run = mn;
      l_run *= fsc;
#pragma unroll
      for (int dt = 0; dt < 4; ++dt)
#pragma unroll
        for (int e = 0; e < 16; ++e) o[dt][e] *= fsc;
    }
    float rs = 0.f;
#pragma unroll
    for (int sub = 0; sub < 2; ++sub)
#pragma unroll
      for (int e = 0; e < 16; ++e) {
        float p = EXP2F(__builtin_fmaf(st[sub][e], sc2, -m_run));
        st[sub][e] = p;
        rs += p;
      }
    rs += __shfl_xor(rs, 32);
    l_run += rs;

    // ---- pack P to bf16 B-fragments: pf[tt] = P[qr][kv = tt*16 + hi*8 + 0..7]
    uint32_t pk[16];
#pragma unroll
    for (int sub = 0; sub < 2; ++sub)
#pragma unroll
      for (int i = 0; i < 8; ++i)
        pk[sub * 8 + i] = pack2(st[sub][2 * i], st[sub][2 * i + 1]);
    uint32_t rv[8];
#pragma unroll
    for (int m = 0; m < 8; ++m) {
      int base = 4 * (m >> 1) + (m & 1);
      uint32_t snd = hi ? pk[base] : pk[base + 2];
      rv[m] = __shfl_xor(snd, 32);
    }
    bf16x8 pf[4];
#pragma unroll
    for (int tt = 0; tt < 4; ++tt) {
      u32x4 wv;
      wv[0] = hi ? rv[2 * tt]     : pk[4 * tt];
      wv[1] = hi ? rv[2 * tt + 1] : pk[4 * tt + 1];
      wv[2] = hi ? pk[4 * tt + 2] : rv[2 * tt];
      wv[3] = hi ? pk[4 * tt + 3] : rv[2 * tt + 1];
      pf[tt] = __builtin_bit_cast(bf16x8, wv);
    }
    // ---- O^T += V^T P^T
    __builtin_amdgcn_s_setprio(1);
#pragma unroll
    for (int dt = 0; dt < 4; ++dt) {
      int dr = dt * 32 + l31;
#pragma unroll
      for (int tt = 0; tt < 4; ++tt) {
        bf16x8 vf = *reinterpret_cast<const bf16x8*>((char*)&Vt[cur][0][0] + dr * 132 + tt * 32 + hi * 16);
        o[dt] = __builtin_amdgcn_mfma_f32_32x32x16_bf16(vf, pf[tt], o[dt], 0, 0, 0);
      }
    }
    __builtin_amdgcn_s_setprio(0);
    // ---- late V^T write for next tile (loads had QK+softmax+PV to land)
    if (t + 1 < nt) write_v(1 - cur);
  }

  // ---- epilogue: transpose O^T -> O via per-wave LDS scratch, coalesced stores
  float inv = 1.f / l_run;
  __bf16* scr = &Ks[0][0] + wq * 1280;               // [32][40] bf16 per wave
  const int qq = lane >> 1, part = lane & 1;
#pragma unroll
  for (int dt = 0; dt < 4; ++dt) {
    __syncthreads();                                 // all waves done reading Ks/Vt (or prev dt)
#pragma unroll
    for (int i = 0; i < 8; ++i) {
      int d0 = (2 * i & 3) + 8 * (i >> 1) + 4 * hi;
      bf16x2 prr;
      prr[0] = (__bf16)(o[dt][2 * i] * inv);
      prr[1] = (__bf16)(o[dt][2 * i + 1] * inv);
      *reinterpret_cast<bf16x2*>(scr + l31 * 40 + d0) = prr;
    }
    __syncthreads();
    bf16x8 r0 = *reinterpret_cast<const bf16x8*>(scr + qq * 40 + part * 16);
    bf16x8 r1 = *reinterpret_cast<const bf16x8*>(scr + qq * 40 + part * 16 + 8);
    __bf16* op = out + (size_t)(q0 + wq * 32 + qq) * DIM_ + head * HD + dt * 32 + part * 16;
    *reinterpret_cast<bf16x8*>(op) = r0;
    *reinterpret_cast<bf16x8*>(op + 8) = r1;
  }
}

// ---------------------------------------------------------------------------
extern "C" void kernel_launch(void* const* d_in, const int* in_sizes, int n_in,
                              void* d_out, int out_size, void* d_ws, size_t ws_size,
                              hipStream_t stream) {
  (void)in_sizes; (void)n_in; (void)out_size; (void)ws_size;
  const float* x    = (const float*)d_in[0];
  const float* fc   = (const float*)d_in[1];
  const float* fs   = (const float*)d_in[2];
  // d_in[3] = mask (causal, hardcoded in attn_kernel)
  const float* wqkv = (const float*)d_in[4];
  const float* wo   = (const float*)d_in[5];
  float* out = (float*)d_out;

  char* ws = (char*)d_ws;
  __bf16* xb    = (__bf16*)(ws);                       // 16,777,216  (reused as attn_out)
  __bf16* wqkvb = (__bf16*)(ws + 16777216);            // 50,331,648
  __bf16* wob   = (__bf16*)(ws + 67108864);            // 33,554,432
  __bf16* qkv   = (__bf16*)(ws + 100663296);           // 25,165,824
  __bf16* attnO = xb;                                  // xb dead after gemm1

  // single fused conversion pass (x, wqkv, wo)
  cvt3<<<2048, 256, 0, stream>>>(x, xb, wqkv, wqkvb, wo, wob);

  // qkv = x @ wqkv^T : 256x256 tiles, 192 blocks, 8-phase (R15 structure).
  g1_8p<<<192, 512, 0, stream>>>(xb, wqkvb, qkv, DIM_, DIM_, DIM_, QKV_LD);

  // rope on Q + K parts (standalone — cheaper than epilogue fusion, R17)
  rope_kernel<<<(S_LEN * 40 * 64) / 256, 256, 0, stream>>>(qkv, fc, fs);

  // causal GQA attention (512 blocks x 256 threads, 2 blocks/CU, paired LPT)
  attn_kernel<<<512, 256, 0, stream>>>(qkv, attnO);

  // out = attnO @ wo^T : M=2048, N=4096, K=4096. 128x256 tiles -> 256 blocks, 2-phase.
  gemm32<128, 256, 16, 2, float><<<256, 512, 0, stream>>>(attnO, wob, out, DIM_, DIM_, DIM_, DIM_);
}

// Round 19
// 321.436 us; speedup vs baseline: 1.0650x; 1.0153x over previous
//
#include <hip/hip_runtime.h>
#include <hip/hip_bf16.h>
#include <cstdint>
#include <cstddef>

// ---------------------------------------------------------------------------
// Attention block: qkv = x @ wqkv^T ; rope(q,k) ; causal GQA attention ; out = att @ wo^T
// B=1, S=2048, DIM=4096, NH=32, NKV=8, HD=128. All compute in bf16 MFMA + f32 accum.
// ---------------------------------------------------------------------------

typedef __attribute__((ext_vector_type(4)))  float    f32x4;
typedef __attribute__((ext_vector_type(16))) float    f32x16;
typedef __attribute__((ext_vector_type(8)))  __bf16   bf16x8;
typedef __attribute__((ext_vector_type(4)))  __bf16   bf16x4;
typedef __attribute__((ext_vector_type(2)))  __bf16   bf16x2;
typedef __attribute__((ext_vector_type(4)))  uint32_t u32x4;

typedef const __attribute__((address_space(1))) void* gaddr_t;
typedef __attribute__((address_space(3))) void*       laddr_t;

#define S_LEN   2048
#define DIM_    4096
#define NHEADS  32
#define NKV     8
#define HD      128
#define QKV_LD  6144   // row stride of qkv buffer (Q|K|V)
#define KOFF    4096
#define VOFF    5120

#define EXP2F(x) __builtin_amdgcn_exp2f(x)   // v_exp_f32 (2^x); __exp2f collides with glibc macro

// ---------------- fused f32 -> bf16 conversion (x, wqkv, wo in one pass) ---
#define N4_X  2097152   // 2048*4096/4
#define N4_W  6291456   // 6144*4096/4
#define N4_O  4194304   // 4096*4096/4
__global__ void cvt3(const float* __restrict__ x, __bf16* __restrict__ xb,
                     const float* __restrict__ wq, __bf16* __restrict__ wqb,
                     const float* __restrict__ wo, __bf16* __restrict__ wob) {
  int idx = blockIdx.x * blockDim.x + threadIdx.x;
  int stride = gridDim.x * blockDim.x;
  for (int i = idx; i < N4_X + N4_W + N4_O; i += stride) {
    const float* src; __bf16* dst; int k;
    if (i < N4_X)            { src = x;  dst = xb;  k = i; }
    else if (i < N4_X + N4_W){ src = wq; dst = wqb; k = i - N4_X; }
    else                     { src = wo; dst = wob; k = i - N4_X - N4_W; }
    float4 v = reinterpret_cast<const float4*>(src)[k];
    bf16x4 o;
    o[0] = (__bf16)v.x; o[1] = (__bf16)v.y; o[2] = (__bf16)v.z; o[3] = (__bf16)v.w;
    reinterpret_cast<bf16x4*>(dst)[k] = o;
  }
}

// ---------------- RoPE in-place on Q and K parts of qkv --------------------
__global__ void rope_kernel(__bf16* __restrict__ qkv, const float* __restrict__ fc,
                            const float* __restrict__ fs) {
  int tid = blockIdx.x * 256 + threadIdx.x;   // 0 .. 2048*40*64-1
  int i = tid & 63;
  int t = tid >> 6;
  int h = t % 40;
  int s = t / 40;
  int col = (h < NHEADS) ? (h * HD + 2 * i) : (KOFF + (h - NHEADS) * HD + 2 * i);
  size_t off = (size_t)s * QKV_LD + col;
  float c = fc[s * 64 + i], sn = fs[s * 64 + i];
  bf16x2 v = *reinterpret_cast<bf16x2*>(&qkv[off]);
  float t0 = (float)v[0], t1 = (float)v[1];
  bf16x2 o;
  o[0] = (__bf16)(t0 * c - t1 * sn);
  o[1] = (__bf16)(t0 * sn + t1 * c);
  *reinterpret_cast<bf16x2*>(&qkv[off]) = o;
}

// ---------------- shared stage op: 64 rows x 128B, swizzled src ------------
__device__ __forceinline__ void stg64(const __bf16* __restrict__ P, int ld, int row0,
                                      int kt, char* dst, int tid) {
  int r = tid >> 3, g = tid & 7;
  int row = row0 + r;
  const __bf16* src = P + (size_t)row * ld + kt * 64 + ((g ^ (row & 7)) * 8);
  __builtin_amdgcn_global_load_lds((gaddr_t)src,
      (laddr_t)(dst + (tid & ~63) * 16), 16, 0, 0);
}

// ==================== gemm1: m201-faithful 8-phase, 256x256 ================
// (R15: verified; ~125 us, MfmaUtil 34%. DO NOT TOUCH.)
template <int QM, int QN, bool RA, bool RB, int VW>   // VW: -1 none, 4, 0
__device__ __forceinline__ void g1_phase(const __bf16* __restrict__ Ab,
                                         const __bf16* __restrict__ Bb,
                                         f32x4 (&acc)[8][4],
                                         bf16x8 (&afr)[4][2], bf16x8 (&bfr)[2][2],
                                         int wm, int wn, int l15, int hi, int tid,
                                         const __bf16* __restrict__ SP, int sld,
                                         int srow, int skt, char* sdst, bool doSt) {
  if constexpr (RA) {
#pragma unroll
    for (int fm = 0; fm < 4; ++fm) {
      int R = wm * 128 + QM * 64 + fm * 16 + l15;
#pragma unroll
      for (int kk = 0; kk < 2; ++kk)
        afr[fm][kk] = *reinterpret_cast<const bf16x8*>(
            (const char*)Ab + R * 128 + (((kk * 4 + hi) ^ (R & 7)) * 16));
    }
  }
  if constexpr (RB) {
#pragma unroll
    for (int fn = 0; fn < 2; ++fn) {
      int R = wn * 64 + QN * 32 + fn * 16 + l15;
#pragma unroll
      for (int kk = 0; kk < 2; ++kk)
        bfr[fn][kk] = *reinterpret_cast<const bf16x8*>(
            (const char*)Bb + R * 128 + (((kk * 4 + hi) ^ (R & 7)) * 16));
    }
  }
  if (doSt) {
    stg64(SP, sld, srow, skt, sdst, tid);
    stg64(SP, sld, srow + 64, skt, sdst + 8192, tid);
  }
  __builtin_amdgcn_s_barrier();
  asm volatile("s_waitcnt lgkmcnt(0)" ::: "memory");
  __builtin_amdgcn_sched_barrier(0);
  __builtin_amdgcn_s_setprio(1);
#pragma unroll
  for (int kk = 0; kk < 2; ++kk)
#pragma unroll
    for (int fm = 0; fm < 4; ++fm)
#pragma unroll
      for (int fn = 0; fn < 2; ++fn)
        acc[QM * 4 + fm][QN * 2 + fn] = __builtin_amdgcn_mfma_f32_16x16x32_bf16(
            afr[fm][kk], bfr[fn][kk], acc[QM * 4 + fm][QN * 2 + fn], 0, 0, 0);
  __builtin_amdgcn_s_setprio(0);
  if constexpr (VW == 4) asm volatile("s_waitcnt vmcnt(4)" ::: "memory");
  if constexpr (VW == 0) asm volatile("s_waitcnt vmcnt(0)" ::: "memory");
  __builtin_amdgcn_s_barrier();
}

// Grid: 192 blocks; xcd = bid&7, lid = bid>>3; m = lid%8, n = xcd*3 + lid/8.
__global__ __launch_bounds__(512) void g1_8p(const __bf16* __restrict__ A,
                                             const __bf16* __restrict__ B,
                                             __bf16* __restrict__ C, int K,
                                             int lda, int ldb, int ldc) {
  __shared__ __align__(16) __bf16 As[2][256 * 64];
  __shared__ __align__(16) __bf16 Bs[2][256 * 64];
  const int tid = threadIdx.x;
  const int l15 = tid & 15, hi = (tid >> 4) & 3, w = tid >> 6;
  const int wm = w >> 2, wn = w & 3;
  const int bid = blockIdx.x, xcd = bid & 7, lid = bid >> 3;
  const int m0 = (lid % 8) * 256;
  const int n0 = (xcd * 3 + lid / 8) * 256;

  f32x4 acc[8][4] = {};
  bf16x8 afr[4][2], bfr[2][2];
  char* A0 = (char*)As[0]; char* A1 = (char*)As[1];
  char* B0 = (char*)Bs[0]; char* B1 = (char*)Bs[1];

  // prologue (FIFO): t0 {A0,B0,A1,B1} -> buf0 ; t1 {A0, B1} -> buf1
  stg64(A, lda, m0,       0, A0,         tid); stg64(A, lda, m0 + 64,  0, A0 + 8192,  tid);
  stg64(B, ldb, n0,       0, B0,         tid); stg64(B, ldb, n0 + 64,  0, B0 + 8192,  tid);
  stg64(A, lda, m0 + 128, 0, A0 + 16384, tid); stg64(A, lda, m0 + 192, 0, A0 + 24576, tid);
  stg64(B, ldb, n0 + 128, 0, B0 + 16384, tid); stg64(B, ldb, n0 + 192, 0, B0 + 24576, tid);
  stg64(A, lda, m0,       1, A1,         tid); stg64(A, lda, m0 + 64,  1, A1 + 8192,  tid);
  stg64(B, ldb, n0 + 128, 1, B1 + 16384, tid); stg64(B, ldb, n0 + 192, 1, B1 + 24576, tid);
  asm volatile("s_waitcnt vmcnt(4)" ::: "memory");   // t0 fully landed; t1 A0,B1 in flight
  __builtin_amdgcn_s_barrier();

  const int nt = K >> 6;                  // 64 K-tiles
  for (int it = 0; it < nt; it += 2) {
    const bool sB = (it + 2 < nt), sC = (it + 3 < nt);
    const bool last = !sB;
    const __bf16* Ab0 = As[0]; const __bf16* Bb0 = Bs[0];
    const __bf16* Ab1 = As[1]; const __bf16* Bb1 = Bs[1];
    // phases 1-4: tile it (buf0)
    g1_phase<0, 0, true,  true, -1>(Ab0, Bb0, acc, afr, bfr, wm, wn, l15, hi, tid,
                                    A, lda, m0 + 128, it + 1, A1 + 16384, true);   // stage t+1:A1
    g1_phase<0, 1, false, true, -1>(Ab0, Bb0, acc, afr, bfr, wm, wn, l15, hi, tid,
                                    B, ldb, n0, it + 1, B1, true);                 // stage t+1:B0
    g1_phase<1, 1, true, false, -1>(Ab0, Bb0, acc, afr, bfr, wm, wn, l15, hi, tid,
                                    A, lda, m0, it + 2, A0, sB);                   // stage t+2:A0
    if (last)
      g1_phase<1, 0, false, true, 0>(Ab0, Bb0, acc, afr, bfr, wm, wn, l15, hi, tid,
                                     B, ldb, n0 + 128, it + 2, B0 + 16384, sB);    // vmcnt(0)
    else
      g1_phase<1, 0, false, true, 4>(Ab0, Bb0, acc, afr, bfr, wm, wn, l15, hi, tid,
                                     B, ldb, n0 + 128, it + 2, B0 + 16384, sB);    // stage t+2:B1
    // phases 5-8: tile it+1 (buf1)
    g1_phase<0, 0, true,  true, -1>(Ab1, Bb1, acc, afr, bfr, wm, wn, l15, hi, tid,
                                    A, lda, m0 + 128, it + 2, A0 + 16384, sB);     // stage t+2:A1
    g1_phase<0, 1, false, true, -1>(Ab1, Bb1, acc, afr, bfr, wm, wn, l15, hi, tid,
                                    B, ldb, n0, it + 2, B0, sB);                   // stage t+2:B0
    g1_phase<1, 1, true, false, -1>(Ab1, Bb1, acc, afr, bfr, wm, wn, l15, hi, tid,
                                    A, lda, m0, it + 3, A1, sC);                   // stage t+3:A0
    if (last)
      g1_phase<1, 0, false, true, 0>(Ab1, Bb1, acc, afr, bfr, wm, wn, l15, hi, tid,
                                     B, ldb, n0 + 128, it + 3, B1 + 16384, sC);
    else
      g1_phase<1, 0, false, true, 4>(Ab1, Bb1, acc, afr, bfr, wm, wn, l15, hi, tid,
                                     B, ldb, n0 + 128, it + 3, B1 + 16384, sC);    // stage t+3:B1
  }

  // epilogue: 16x16 C layout — row = ... + hi*4 + j, col = ... + l15
#pragma unroll
  for (int qm = 0; qm < 2; ++qm)
#pragma unroll
    for (int fm = 0; fm < 4; ++fm)
#pragma unroll
      for (int qn = 0; qn < 2; ++qn)
#pragma unroll
        for (int fn = 0; fn < 2; ++fn)
#pragma unroll
          for (int j = 0; j < 4; ++j) {
            int row = m0 + wm * 128 + qm * 64 + fm * 16 + hi * 4 + j;
            int col = n0 + wn * 64 + qn * 32 + fn * 16 + l15;
            C[(size_t)row * ldc + col] = (__bf16)acc[qm * 4 + fm][qn * 2 + fn][j];
          }
}

// ==================== gemm2: 8-phase port, 128x256, 256 blocks =============
// Mirror of g1's verified schedule at BM=128: A half = 1 stg64, B half = 2.
// Per 4-phase group stages {t+1:A1, t+1:B0, t+2:A0, t+2:B1}; vmcnt(3) at
// phases 4/8 (FIFO: drains exactly t+1's 6 loads, leaves t+2's 3 in flight);
// vmcnt(0) last tile only.
template <int QM, int QN, bool RA, bool RB, int VW, int NS>  // VW: -1/3/0
__device__ __forceinline__ void g2_phase(const __bf16* __restrict__ Ab,
                                         const __bf16* __restrict__ Bb,
                                         f32x4 (&acc)[4][4],
                                         bf16x8 (&afr)[2][2], bf16x8 (&bfr)[2][2],
                                         int wm, int wn, int l15, int hi, int tid,
                                         const __bf16* __restrict__ SP, int sld,
                                         int srow, int skt, char* sdst, bool doSt) {
  if constexpr (RA) {
#pragma unroll
    for (int fm = 0; fm < 2; ++fm) {
      int R = wm * 64 + QM * 32 + fm * 16 + l15;
#pragma unroll
      for (int kk = 0; kk < 2; ++kk)
        afr[fm][kk] = *reinterpret_cast<const bf16x8*>(
            (const char*)Ab + R * 128 + (((kk * 4 + hi) ^ (R & 7)) * 16));
    }
  }
  if constexpr (RB) {
#pragma unroll
    for (int fn = 0; fn < 2; ++fn) {
      int R = wn * 64 + QN * 32 + fn * 16 + l15;
#pragma unroll
      for (int kk = 0; kk < 2; ++kk)
        bfr[fn][kk] = *reinterpret_cast<const bf16x8*>(
            (const char*)Bb + R * 128 + (((kk * 4 + hi) ^ (R & 7)) * 16));
    }
  }
  if (doSt) {
#pragma unroll
    for (int s = 0; s < NS; ++s)
      stg64(SP, sld, srow + s * 64, skt, sdst + s * 8192, tid);
  }
  __builtin_amdgcn_s_barrier();
  asm volatile("s_waitcnt lgkmcnt(0)" ::: "memory");
  __builtin_amdgcn_sched_barrier(0);
  __builtin_amdgcn_s_setprio(1);
#pragma unroll
  for (int kk = 0; kk < 2; ++kk)
#pragma unroll
    for (int fm = 0; fm < 2; ++fm)
#pragma unroll
      for (int fn = 0; fn < 2; ++fn)
        acc[QM * 2 + fm][QN * 2 + fn] = __builtin_amdgcn_mfma_f32_16x16x32_bf16(
            afr[fm][kk], bfr[fn][kk], acc[QM * 2 + fm][QN * 2 + fn], 0, 0, 0);
  __builtin_amdgcn_s_setprio(0);
  if constexpr (VW == 3) asm volatile("s_waitcnt vmcnt(3)" ::: "memory");
  if constexpr (VW == 0) asm volatile("s_waitcnt vmcnt(0)" ::: "memory");
  __builtin_amdgcn_s_barrier();
}

// Grid: 256 blocks; xcd = bid&7, lid = bid>>3; m = lid%16, n = xcd*2 + lid/16.
__global__ __launch_bounds__(512) void g2_8p(const __bf16* __restrict__ A,
                                             const __bf16* __restrict__ B,
                                             float* __restrict__ C, int K,
                                             int lda, int ldb, int ldc) {
  __shared__ __align__(16) __bf16 As[2][128 * 64];
  __shared__ __align__(16) __bf16 Bs[2][256 * 64];
  const int tid = threadIdx.x;
  const int l15 = tid & 15, hi = (tid >> 4) & 3, w = tid >> 6;
  const int wm = w >> 2, wn = w & 3;
  const int bid = blockIdx.x, xcd = bid & 7, lid = bid >> 3;
  const int m0 = (lid % 16) * 128;
  const int n0 = (xcd * 2 + lid / 16) * 256;

  f32x4 acc[4][4] = {};
  bf16x8 afr[2][2], bfr[2][2];
  char* A0 = (char*)As[0]; char* A1 = (char*)As[1];
  char* B0 = (char*)Bs[0]; char* B1 = (char*)Bs[1];

  // prologue (FIFO): t0 {A0(1),B0(2),A1(1),B1(2)} -> buf0 ; t1 {A0(1), B1(2)} -> buf1
  stg64(A, lda, m0,       0, A0,         tid);
  stg64(B, ldb, n0,       0, B0,         tid); stg64(B, ldb, n0 + 64,  0, B0 + 8192,  tid);
  stg64(A, lda, m0 + 64,  0, A0 + 8192,  tid);
  stg64(B, ldb, n0 + 128, 0, B0 + 16384, tid); stg64(B, ldb, n0 + 192, 0, B0 + 24576, tid);
  stg64(A, lda, m0,       1, A1,         tid);
  stg64(B, ldb, n0 + 128, 1, B1 + 16384, tid); stg64(B, ldb, n0 + 192, 1, B1 + 24576, tid);
  asm volatile("s_waitcnt vmcnt(3)" ::: "memory");   // t0 landed; t1 A0,B1 in flight
  __builtin_amdgcn_s_barrier();

  const int nt = K >> 6;
  for (int it = 0; it < nt; it += 2) {
    const bool sB = (it + 2 < nt), sC = (it + 3 < nt);
    const bool last = !sB;
    const __bf16* Ab0 = As[0]; const __bf16* Bb0 = Bs[0];
    const __bf16* Ab1 = As[1]; const __bf16* Bb1 = Bs[1];
    // phases 1-4: tile it (buf0)
    g2_phase<0, 0, true,  true, -1, 1>(Ab0, Bb0, acc, afr, bfr, wm, wn, l15, hi, tid,
                                       A, lda, m0 + 64, it + 1, A1 + 8192, true);  // t+1:A1
    g2_phase<0, 1, false, true, -1, 2>(Ab0, Bb0, acc, afr, bfr, wm, wn, l15, hi, tid,
                                       B, ldb, n0, it + 1, B1, true);              // t+1:B0
    g2_phase<1, 1, true, false, -1, 1>(Ab0, Bb0, acc, afr, bfr, wm, wn, l15, hi, tid,
                                       A, lda, m0, it + 2, A0, sB);                // t+2:A0
    if (last)
      g2_phase<1, 0, false, true, 0, 2>(Ab0, Bb0, acc, afr, bfr, wm, wn, l15, hi, tid,
                                        B, ldb, n0 + 128, it + 2, B0 + 16384, sB);
    else
      g2_phase<1, 0, false, true, 3, 2>(Ab0, Bb0, acc, afr, bfr, wm, wn, l15, hi, tid,
                                        B, ldb, n0 + 128, it + 2, B0 + 16384, sB); // t+2:B1
    // phases 5-8: tile it+1 (buf1)
    g2_phase<0, 0, true,  true, -1, 1>(Ab1, Bb1, acc, afr, bfr, wm, wn, l15, hi, tid,
                                       A, lda, m0 + 64, it + 2, A0 + 8192, sB);    // t+2:A1
    g2_phase<0, 1, false, true, -1, 2>(Ab1, Bb1, acc, afr, bfr, wm, wn, l15, hi, tid,
                                       B, ldb, n0, it + 2, B0, sB);                // t+2:B0
    g2_phase<1, 1, true, false, -1, 1>(Ab1, Bb1, acc, afr, bfr, wm, wn, l15, hi, tid,
                                       A, lda, m0, it + 3, A1, sC);                // t+3:A0
    if (last)
      g2_phase<1, 0, false, true, 0, 2>(Ab1, Bb1, acc, afr, bfr, wm, wn, l15, hi, tid,
                                        B, ldb, n0 + 128, it + 3, B1 + 16384, sC);
    else
      g2_phase<1, 0, false, true, 3, 2>(Ab1, Bb1, acc, afr, bfr, wm, wn, l15, hi, tid,
                                        B, ldb, n0 + 128, it + 3, B1 + 16384, sC); // t+3:B1
  }

  // epilogue: row = m0 + wm*64 + qm*32 + fm*16 + hi*4 + j, col = n0 + wn*64 + qn*32 + fn*16 + l15
#pragma unroll
  for (int qm = 0; qm < 2; ++qm)
#pragma unroll
    for (int fm = 0; fm < 2; ++fm)
#pragma unroll
      for (int qn = 0; qn < 2; ++qn)
#pragma unroll
        for (int fn = 0; fn < 2; ++fn)
#pragma unroll
          for (int j = 0; j < 4; ++j) {
            int row = m0 + wm * 64 + qm * 32 + fm * 16 + hi * 4 + j;
            int col = n0 + wn * 64 + qn * 32 + fn * 16 + l15;
            C[(size_t)row * ldc + col] = acc[qm * 2 + fm][qn * 2 + fn][j];
          }
}

// ---------------- Flash attention, causal, GQA — staged K/V, 2 blocks/CU ---
// 512 blocks x 256 thr (4 waves x 32 q-rows, QBLK=128). Static-index V^T
// staging (stride 66), scale folded into exp2 fma, setprio around MFMA.
__device__ inline uint32_t pack2(float a, float b) {
  bf16x2 t; t[0] = (__bf16)a; t[1] = (__bf16)b;
  return __builtin_bit_cast(uint32_t, t);
}

__global__ __launch_bounds__(256, 2) void attn_kernel(const __bf16* __restrict__ qkv,
                                                      __bf16* __restrict__ out) {
  __shared__ __align__(16) __bf16 Ks[2][64 * 128];   // XOR-swizzled 16B groups
  __shared__ __align__(16) __bf16 Vt[2][128][66];    // V^T, stride 132B
  const int tid = threadIdx.x;
  const int lane = tid & 63, l31 = lane & 31, hi = lane >> 5, wq = tid >> 6;
  const int head = blockIdx.x & 31;
  const int g = blockIdx.x >> 5;                     // 0..15
  const int qt = (g < 8) ? (15 - g) : (g - 8);       // LPT + slot pairing
  const int q0 = qt * 128;
  const int nt = 2 * qt + 2;                         // kv tiles (causal)
  const int kvh = head >> 2;
  const float sc2 = 0.08838834764831845f * 1.44269504089f;  // 1/sqrt(128)*log2(e)
  const int qr = q0 + wq * 32 + l31;                 // this lane's q row

  bf16x8 vr[2][2];  // in-flight V rows (2 tasks x 2 rows)

  auto stage_k = [&](int tt, int buf) {
#pragma unroll
    for (int i = 0; i < 4; ++i) {
      int c = i * 256 + tid;                         // 16B chunk 0..1023
      int r = c >> 4, gg = c & 15;
      const __bf16* gk = qkv + (size_t)(tt * 64 + r) * QKV_LD + KOFF + kvh * HD + ((gg ^ (r & 7)) * 8);
      __builtin_amdgcn_global_load_lds((gaddr_t)gk,
          (laddr_t)((char*)Ks[buf] + (tid & ~63) * 16 + i * 4096), 16, 0, 0);
    }
  };
  auto load_v = [&](int tt) {
#pragma unroll
    for (int i = 0; i < 2; ++i) {
      int task = i * 256 + tid;                      // 0..511
      int p = task >> 4, cg = task & 15;
      const __bf16* vp = qkv + (size_t)(tt * 64 + 2 * p) * QKV_LD + VOFF + kvh * HD + cg * 8;
      vr[i][0] = *reinterpret_cast<const bf16x8*>(vp);
      vr[i][1] = *reinterpret_cast<const bf16x8*>(vp + QKV_LD);
    }
  };
  auto write_v = [&](int buf) {
#pragma unroll
    for (int i = 0; i < 2; ++i) {
      int task = i * 256 + tid;
      int p = task >> 4, cg = task & 15;
#pragma unroll
      for (int e = 0; e < 8; ++e) {                  // STATIC index — no select trees
        bf16x2 pkv; pkv[0] = vr[i][0][e]; pkv[1] = vr[i][1][e];
        *reinterpret_cast<bf16x2*>(&Vt[buf][cg * 8 + e][2 * p]) = pkv;
      }
    }
  };

  // Q fragments (B-layout): lane holds Q[qr][k = ks*16 + hi*8 + 0..7]
  bf16x8 qf[8];
  {
    const __bf16* qp = qkv + (size_t)qr * QKV_LD + head * HD + hi * 8;
#pragma unroll
    for (int ks = 0; ks < 8; ++ks) qf[ks] = *reinterpret_cast<const bf16x8*>(qp + ks * 16);
  }
  f32x16 o[4] = {};
  float m_run = -3e38f, l_run = 0.f;

  stage_k(0, 0); load_v(0); write_v(0);

  for (int t = 0; t < nt; ++t) {
    const int cur = t & 1;
    __syncthreads();        // staging of buf[cur] visible; prev reads of buf[1-cur] done
    if (t + 1 < nt) { stage_k(t + 1, 1 - cur); load_v(t + 1); }

    // ---- S^T = K Q^T : col=q=l31, row=(e&3)+8*(e>>2)+4*hi  (RAW scores)
    f32x16 st[2];
    __builtin_amdgcn_s_setprio(1);
#pragma unroll
    for (int sub = 0; sub < 2; ++sub) {
      f32x16 acc = {};
      int r = sub * 32 + l31;
#pragma unroll
      for (int ks = 0; ks < 8; ++ks) {
        int gg = (ks * 2 + hi) ^ (r & 7);
        bf16x8 kf = *reinterpret_cast<const bf16x8*>((char*)Ks[cur] + r * 256 + gg * 16);
        acc = __builtin_amdgcn_mfma_f32_32x32x16_bf16(kf, qf[ks], acc, 0, 0, 0);
      }
      st[sub] = acc;
    }
    __builtin_amdgcn_s_setprio(0);
    if (t >= nt - 2) {      // only the two diagonal tiles need masking
      const int kv0 = t * 64;
#pragma unroll
      for (int sub = 0; sub < 2; ++sub)
#pragma unroll
        for (int e = 0; e < 16; ++e) {
          int kvg = kv0 + sub * 32 + (e & 3) + 8 * (e >> 2) + 4 * hi;
          if (kvg > qr) st[sub][e] = -1e30f;
        }
    }
    // ---- online softmax (lane-local, defer-max, scale folded into exp2 fma)
    float pm = st[0][0];
#pragma unroll
    for (int e = 1; e < 16; ++e) pm = fmaxf(pm, st[0][e]);
#pragma unroll
    for (int e = 0; e < 16; ++e) pm = fmaxf(pm, st[1][e]);
    pm = fmaxf(pm, __shfl_xor(pm, 32));
    pm *= sc2;                                       // to scaled domain
    if (!__all(pm - m_run <= 8.f)) {
      float mn = fmaxf(m_run, pm);
      float fsc = EXP2F(m_run - mn);
      m_run = mn;
      l_run *= fsc;
#pragma unroll
      for (int dt = 0; dt < 4; ++dt)
#pragma unroll
        for (int e = 0; e < 16; ++e) o[dt][e] *= fsc;
    }
    float rs = 0.f;
#pragma unroll
    for (int sub = 0; sub < 2; ++sub)
#pragma unroll
      for (int e = 0; e < 16; ++e) {
        float p = EXP2F(__builtin_fmaf(st[sub][e], sc2, -m_run));
        st[sub][e] = p;
        rs += p;
      }
    rs += __shfl_xor(rs, 32);
    l_run += rs;

    // ---- pack P to bf16 B-fragments: pf[tt] = P[qr][kv = tt*16 + hi*8 + 0..7]
    uint32_t pk[16];
#pragma unroll
    for (int sub = 0; sub < 2; ++sub)
#pragma unroll
      for (int i = 0; i < 8; ++i)
        pk[sub * 8 + i] = pack2(st[sub][2 * i], st[sub][2 * i + 1]);
    uint32_t rv[8];
#pragma unroll
    for (int m = 0; m < 8; ++m) {
      int base = 4 * (m >> 1) + (m & 1);
      uint32_t snd = hi ? pk[base] : pk[base + 2];
      rv[m] = __shfl_xor(snd, 32);
    }
    bf16x8 pf[4];
#pragma unroll
    for (int tt = 0; tt < 4; ++tt) {
      u32x4 wv;
      wv[0] = hi ? rv[2 * tt]     : pk[4 * tt];
      wv[1] = hi ? rv[2 * tt + 1] : pk[4 * tt + 1];
      wv[2] = hi ? pk[4 * tt + 2] : rv[2 * tt];
      wv[3] = hi ? pk[4 * tt + 3] : rv[2 * tt + 1];
      pf[tt] = __builtin_bit_cast(bf16x8, wv);
    }
    // ---- O^T += V^T P^T
    __builtin_amdgcn_s_setprio(1);
#pragma unroll
    for (int dt = 0; dt < 4; ++dt) {
      int dr = dt * 32 + l31;
#pragma unroll
      for (int tt = 0; tt < 4; ++tt) {
        bf16x8 vf = *reinterpret_cast<const bf16x8*>((char*)&Vt[cur][0][0] + dr * 132 + tt * 32 + hi * 16);
        o[dt] = __builtin_amdgcn_mfma_f32_32x32x16_bf16(vf, pf[tt], o[dt], 0, 0, 0);
      }
    }
    __builtin_amdgcn_s_setprio(0);
    // ---- late V^T write for next tile (loads had QK+softmax+PV to land)
    if (t + 1 < nt) write_v(1 - cur);
  }

  // ---- epilogue: transpose O^T -> O via per-wave LDS scratch, coalesced stores
  float inv = 1.f / l_run;
  __bf16* scr = &Ks[0][0] + wq * 1280;               // [32][40] bf16 per wave
  const int qq = lane >> 1, part = lane & 1;
#pragma unroll
  for (int dt = 0; dt < 4; ++dt) {
    __syncthreads();                                 // all waves done reading Ks/Vt (or prev dt)
#pragma unroll
    for (int i = 0; i < 8; ++i) {
      int d0 = (2 * i & 3) + 8 * (i >> 1) + 4 * hi;
      bf16x2 prr;
      prr[0] = (__bf16)(o[dt][2 * i] * inv);
      prr[1] = (__bf16)(o[dt][2 * i + 1] * inv);
      *reinterpret_cast<bf16x2*>(scr + l31 * 40 + d0) = prr;
    }
    __syncthreads();
    bf16x8 r0 = *reinterpret_cast<const bf16x8*>(scr + qq * 40 + part * 16);
    bf16x8 r1 = *reinterpret_cast<const bf16x8*>(scr + qq * 40 + part * 16 + 8);
    __bf16* op = out + (size_t)(q0 + wq * 32 + qq) * DIM_ + head * HD + dt * 32 + part * 16;
    *reinterpret_cast<bf16x8*>(op) = r0;
    *reinterpret_cast<bf16x8*>(op + 8) = r1;
  }
}

// ---------------------------------------------------------------------------
extern "C" void kernel_launch(void* const* d_in, const int* in_sizes, int n_in,
                              void* d_out, int out_size, void* d_ws, size_t ws_size,
                              hipStream_t stream) {
  (void)in_sizes; (void)n_in; (void)out_size; (void)ws_size;
  const float* x    = (const float*)d_in[0];
  const float* fc   = (const float*)d_in[1];
  const float* fs   = (const float*)d_in[2];
  // d_in[3] = mask (causal, hardcoded in attn_kernel)
  const float* wqkv = (const float*)d_in[4];
  const float* wo   = (const float*)d_in[5];
  float* out = (float*)d_out;

  char* ws = (char*)d_ws;
  __bf16* xb    = (__bf16*)(ws);                       // 16,777,216  (reused as attn_out)
  __bf16* wqkvb = (__bf16*)(ws + 16777216);            // 50,331,648
  __bf16* wob   = (__bf16*)(ws + 67108864);            // 33,554,432
  __bf16* qkv   = (__bf16*)(ws + 100663296);           // 25,165,824
  __bf16* attnO = xb;                                  // xb dead after gemm1

  // single fused conversion pass (x, wqkv, wo)
  cvt3<<<2048, 256, 0, stream>>>(x, xb, wqkv, wqkvb, wo, wob);

  // qkv = x @ wqkv^T : 256x256 tiles, 192 blocks, 8-phase (R15 structure).
  g1_8p<<<192, 512, 0, stream>>>(xb, wqkvb, qkv, DIM_, DIM_, DIM_, QKV_LD);

  // rope on Q + K parts (standalone — cheaper than epilogue fusion, R17)
  rope_kernel<<<(S_LEN * 40 * 64) / 256, 256, 0, stream>>>(qkv, fc, fs);

  // causal GQA attention (512 blocks x 256 threads, 2 blocks/CU, paired LPT)
  attn_kernel<<<512, 256, 0, stream>>>(qkv, attnO);

  // out = attnO @ wo^T : 128x256 tiles, 256 blocks, 8-phase (g1 mirror).
  g2_8p<<<256, 512, 0, stream>>>(attnO, wob, out, DIM_, DIM_, DIM_, DIM_);
}

// Round 20
// 317.934 us; speedup vs baseline: 1.0767x; 1.0110x over previous
//
#include <hip/hip_runtime.h>
#include <hip/hip_bf16.h>
#include <cstdint>
#include <cstddef>

// ---------------------------------------------------------------------------
// Attention block: qkv = x @ wqkv^T ; rope(q,k) ; causal GQA attention ; out = att @ wo^T
// B=1, S=2048, DIM=4096, NH=32, NKV=8, HD=128. All compute in bf16 MFMA + f32 accum.
// ---------------------------------------------------------------------------

typedef __attribute__((ext_vector_type(4)))  float    f32x4;
typedef __attribute__((ext_vector_type(16))) float    f32x16;
typedef __attribute__((ext_vector_type(8)))  __bf16   bf16x8;
typedef __attribute__((ext_vector_type(4)))  __bf16   bf16x4;
typedef __attribute__((ext_vector_type(2)))  __bf16   bf16x2;
typedef __attribute__((ext_vector_type(4)))  uint32_t u32x4;

typedef const __attribute__((address_space(1))) void* gaddr_t;
typedef __attribute__((address_space(3))) void*       laddr_t;

#define S_LEN   2048
#define DIM_    4096
#define NHEADS  32
#define NKV     8
#define HD      128
#define QKV_LD  6144   // row stride of qkv buffer (Q|K|V)
#define KOFF    4096
#define VOFF    5120

#define EXP2F(x) __builtin_amdgcn_exp2f(x)   // v_exp_f32 (2^x); __exp2f collides with glibc macro

// ---------------- fused f32 -> bf16 conversion (x, wqkv, wo in one pass) ---
#define N4_X  2097152   // 2048*4096/4
#define N4_W  6291456   // 6144*4096/4
#define N4_O  4194304   // 4096*4096/4
__global__ void cvt3(const float* __restrict__ x, __bf16* __restrict__ xb,
                     const float* __restrict__ wq, __bf16* __restrict__ wqb,
                     const float* __restrict__ wo, __bf16* __restrict__ wob) {
  int idx = blockIdx.x * blockDim.x + threadIdx.x;
  int stride = gridDim.x * blockDim.x;
  for (int i = idx; i < N4_X + N4_W + N4_O; i += stride) {
    const float* src; __bf16* dst; int k;
    if (i < N4_X)            { src = x;  dst = xb;  k = i; }
    else if (i < N4_X + N4_W){ src = wq; dst = wqb; k = i - N4_X; }
    else                     { src = wo; dst = wob; k = i - N4_X - N4_W; }
    float4 v = reinterpret_cast<const float4*>(src)[k];
    bf16x4 o;
    o[0] = (__bf16)v.x; o[1] = (__bf16)v.y; o[2] = (__bf16)v.z; o[3] = (__bf16)v.w;
    reinterpret_cast<bf16x4*>(dst)[k] = o;
  }
}

// ---------------- RoPE in-place on Q and K parts of qkv --------------------
__global__ void rope_kernel(__bf16* __restrict__ qkv, const float* __restrict__ fc,
                            const float* __restrict__ fs) {
  int tid = blockIdx.x * 256 + threadIdx.x;   // 0 .. 2048*40*64-1
  int i = tid & 63;
  int t = tid >> 6;
  int h = t % 40;
  int s = t / 40;
  int col = (h < NHEADS) ? (h * HD + 2 * i) : (KOFF + (h - NHEADS) * HD + 2 * i);
  size_t off = (size_t)s * QKV_LD + col;
  float c = fc[s * 64 + i], sn = fs[s * 64 + i];
  bf16x2 v = *reinterpret_cast<bf16x2*>(&qkv[off]);
  float t0 = (float)v[0], t1 = (float)v[1];
  bf16x2 o;
  o[0] = (__bf16)(t0 * c - t1 * sn);
  o[1] = (__bf16)(t0 * sn + t1 * c);
  *reinterpret_cast<bf16x2*>(&qkv[off]) = o;
}

// ---------------- shared stage op: 64 rows x 128B, swizzled src ------------
__device__ __forceinline__ void stg64(const __bf16* __restrict__ P, int ld, int row0,
                                      int kt, char* dst, int tid) {
  int r = tid >> 3, g = tid & 7;
  int row = row0 + r;
  const __bf16* src = P + (size_t)row * ld + kt * 64 + ((g ^ (row & 7)) * 8);
  __builtin_amdgcn_global_load_lds((gaddr_t)src,
      (laddr_t)(dst + (tid & ~63) * 16), 16, 0, 0);
}

// ==================== gemm1: 8-phase, 128x384 tiles, 256 blocks ============
// R19 experiment: same verified 8-phase schedule as the R15 256x256 version
// (125 us @ 192 blocks = 75% CUs), reshaped to 16x16 = 256 blocks = 100% CUs.
// Per-wave 64x96 (acc[4][6]); 12 MFMA/phase; A half = 1 stg64, B half = 3.
// Group stages {t+1:A1(1), t+1:B0(3), t+2:A0(1), t+2:B1(3)}; vmcnt(4) at
// phases 4/8 drains exactly the next tile's 8 loads (4 stay in flight).
template <int QM, int QN, bool RA, bool RB, int VW, int NS>  // VW: -1/4/0
__device__ __forceinline__ void g1_phase(const __bf16* __restrict__ Ab,
                                         const __bf16* __restrict__ Bb,
                                         f32x4 (&acc)[4][6],
                                         bf16x8 (&afr)[2][2], bf16x8 (&bfr)[3][2],
                                         int wm, int wn, int l15, int hi, int tid,
                                         const __bf16* __restrict__ SP, int sld,
                                         int srow, int skt, char* sdst, bool doSt) {
  if constexpr (RA) {
#pragma unroll
    for (int fm = 0; fm < 2; ++fm) {
      int R = wm * 64 + QM * 32 + fm * 16 + l15;
#pragma unroll
      for (int kk = 0; kk < 2; ++kk)
        afr[fm][kk] = *reinterpret_cast<const bf16x8*>(
            (const char*)Ab + R * 128 + (((kk * 4 + hi) ^ (R & 7)) * 16));
    }
  }
  if constexpr (RB) {
#pragma unroll
    for (int fn = 0; fn < 3; ++fn) {
      int R = wn * 96 + QN * 48 + fn * 16 + l15;
#pragma unroll
      for (int kk = 0; kk < 2; ++kk)
        bfr[fn][kk] = *reinterpret_cast<const bf16x8*>(
            (const char*)Bb + R * 128 + (((kk * 4 + hi) ^ (R & 7)) * 16));
    }
  }
  if (doSt) {
#pragma unroll
    for (int s = 0; s < NS; ++s)
      stg64(SP, sld, srow + s * 64, skt, sdst + s * 8192, tid);
  }
  __builtin_amdgcn_s_barrier();
  asm volatile("s_waitcnt lgkmcnt(0)" ::: "memory");
  __builtin_amdgcn_sched_barrier(0);
  __builtin_amdgcn_s_setprio(1);
#pragma unroll
  for (int kk = 0; kk < 2; ++kk)
#pragma unroll
    for (int fm = 0; fm < 2; ++fm)
#pragma unroll
      for (int fn = 0; fn < 3; ++fn)
        acc[QM * 2 + fm][QN * 3 + fn] = __builtin_amdgcn_mfma_f32_16x16x32_bf16(
            afr[fm][kk], bfr[fn][kk], acc[QM * 2 + fm][QN * 3 + fn], 0, 0, 0);
  __builtin_amdgcn_s_setprio(0);
  if constexpr (VW == 4) asm volatile("s_waitcnt vmcnt(4)" ::: "memory");
  if constexpr (VW == 0) asm volatile("s_waitcnt vmcnt(0)" ::: "memory");
  __builtin_amdgcn_s_barrier();
}

// Grid: 256 blocks; xcd=bid&7, lid=bid>>3; XCD chunk 4m x 8n.
__global__ __launch_bounds__(512) void g1_8p(const __bf16* __restrict__ A,
                                             const __bf16* __restrict__ B,
                                             __bf16* __restrict__ C, int K,
                                             int lda, int ldb, int ldc) {
  __shared__ __align__(16) __bf16 As[2][128 * 64];   // 32 KB
  __shared__ __align__(16) __bf16 Bs[2][384 * 64];   // 96 KB
  const int tid = threadIdx.x;
  const int l15 = tid & 15, hi = (tid >> 4) & 3, w = tid >> 6;
  const int wm = w >> 2, wn = w & 3;
  const int bid = blockIdx.x, xcd = bid & 7, lid = bid >> 3;
  const int m0 = ((xcd >> 1) * 4 + (lid & 3)) * 128;
  const int n0 = ((xcd & 1) * 8 + (lid >> 2)) * 384;

  f32x4 acc[4][6] = {};
  bf16x8 afr[2][2], bfr[3][2];
  char* A0 = (char*)As[0]; char* A1 = (char*)As[1];
  char* B0 = (char*)Bs[0]; char* B1 = (char*)Bs[1];
  const int Bh = 192 * 128;               // byte offset of B half1 (24576)

  // prologue (FIFO): t0 {A0(1),B0(3),A1(1),B1(3)} -> buf0 ; t1 {A0(1), B1(3)} -> buf1
  stg64(A, lda, m0,       0, A0,         tid);
  stg64(B, ldb, n0,       0, B0,         tid); stg64(B, ldb, n0 + 64,  0, B0 + 8192, tid);
  stg64(B, ldb, n0 + 128, 0, B0 + 16384, tid);
  stg64(A, lda, m0 + 64,  0, A0 + 8192,  tid);
  stg64(B, ldb, n0 + 192, 0, B0 + Bh,         tid);
  stg64(B, ldb, n0 + 256, 0, B0 + Bh + 8192,  tid);
  stg64(B, ldb, n0 + 320, 0, B0 + Bh + 16384, tid);
  stg64(A, lda, m0,       1, A1,         tid);
  stg64(B, ldb, n0 + 192, 1, B1 + Bh,         tid);
  stg64(B, ldb, n0 + 256, 1, B1 + Bh + 8192,  tid);
  stg64(B, ldb, n0 + 320, 1, B1 + Bh + 16384, tid);
  asm volatile("s_waitcnt vmcnt(4)" ::: "memory");   // t0 landed; t1 A0,B1 in flight
  __builtin_amdgcn_s_barrier();

  const int nt = K >> 6;                  // 64 K-tiles
  for (int it = 0; it < nt; it += 2) {
    const bool sB = (it + 2 < nt), sC = (it + 3 < nt);
    const bool last = !sB;
    const __bf16* Ab0 = As[0]; const __bf16* Bb0 = Bs[0];
    const __bf16* Ab1 = As[1]; const __bf16* Bb1 = Bs[1];
    // phases 1-4: tile it (buf0)
    g1_phase<0, 0, true,  true, -1, 1>(Ab0, Bb0, acc, afr, bfr, wm, wn, l15, hi, tid,
                                       A, lda, m0 + 64, it + 1, A1 + 8192, true);   // t+1:A1
    g1_phase<0, 1, false, true, -1, 3>(Ab0, Bb0, acc, afr, bfr, wm, wn, l15, hi, tid,
                                       B, ldb, n0, it + 1, B1, true);               // t+1:B0
    g1_phase<1, 1, true, false, -1, 1>(Ab0, Bb0, acc, afr, bfr, wm, wn, l15, hi, tid,
                                       A, lda, m0, it + 2, A0, sB);                 // t+2:A0
    if (last)
      g1_phase<1, 0, false, true, 0, 3>(Ab0, Bb0, acc, afr, bfr, wm, wn, l15, hi, tid,
                                        B, ldb, n0 + 192, it + 2, B0 + Bh, sB);
    else
      g1_phase<1, 0, false, true, 4, 3>(Ab0, Bb0, acc, afr, bfr, wm, wn, l15, hi, tid,
                                        B, ldb, n0 + 192, it + 2, B0 + Bh, sB);     // t+2:B1
    // phases 5-8: tile it+1 (buf1)
    g1_phase<0, 0, true,  true, -1, 1>(Ab1, Bb1, acc, afr, bfr, wm, wn, l15, hi, tid,
                                       A, lda, m0 + 64, it + 2, A0 + 8192, sB);     // t+2:A1
    g1_phase<0, 1, false, true, -1, 3>(Ab1, Bb1, acc, afr, bfr, wm, wn, l15, hi, tid,
                                       B, ldb, n0, it + 2, B0, sB);                 // t+2:B0
    g1_phase<1, 1, true, false, -1, 1>(Ab1, Bb1, acc, afr, bfr, wm, wn, l15, hi, tid,
                                       A, lda, m0, it + 3, A1, sC);                 // t+3:A0
    if (last)
      g1_phase<1, 0, false, true, 0, 3>(Ab1, Bb1, acc, afr, bfr, wm, wn, l15, hi, tid,
                                        B, ldb, n0 + 192, it + 3, B1 + Bh, sC);
    else
      g1_phase<1, 0, false, true, 4, 3>(Ab1, Bb1, acc, afr, bfr, wm, wn, l15, hi, tid,
                                        B, ldb, n0 + 192, it + 3, B1 + Bh, sC);     // t+3:B1
  }

  // epilogue: row = m0 + wm*64 + qm*32 + fm*16 + hi*4 + j ; col = n0 + wn*96 + qn*48 + fn*16 + l15
#pragma unroll
  for (int qm = 0; qm < 2; ++qm)
#pragma unroll
    for (int fm = 0; fm < 2; ++fm)
#pragma unroll
      for (int qn = 0; qn < 2; ++qn)
#pragma unroll
        for (int fn = 0; fn < 3; ++fn)
#pragma unroll
          for (int j = 0; j < 4; ++j) {
            int row = m0 + wm * 64 + qm * 32 + fm * 16 + hi * 4 + j;
            int col = n0 + wn * 96 + qn * 48 + fn * 16 + l15;
            C[(size_t)row * ldc + col] = (__bf16)acc[qm * 2 + fm][qn * 3 + fn][j];
          }
}

// ==================== gemm2: 8-phase, 128x256, 256 blocks (R19-proven) =====
template <int QM, int QN, bool RA, bool RB, int VW, int NS>  // VW: -1/3/0
__device__ __forceinline__ void g2_phase(const __bf16* __restrict__ Ab,
                                         const __bf16* __restrict__ Bb,
                                         f32x4 (&acc)[4][4],
                                         bf16x8 (&afr)[2][2], bf16x8 (&bfr)[2][2],
                                         int wm, int wn, int l15, int hi, int tid,
                                         const __bf16* __restrict__ SP, int sld,
                                         int srow, int skt, char* sdst, bool doSt) {
  if constexpr (RA) {
#pragma unroll
    for (int fm = 0; fm < 2; ++fm) {
      int R = wm * 64 + QM * 32 + fm * 16 + l15;
#pragma unroll
      for (int kk = 0; kk < 2; ++kk)
        afr[fm][kk] = *reinterpret_cast<const bf16x8*>(
            (const char*)Ab + R * 128 + (((kk * 4 + hi) ^ (R & 7)) * 16));
    }
  }
  if constexpr (RB) {
#pragma unroll
    for (int fn = 0; fn < 2; ++fn) {
      int R = wn * 64 + QN * 32 + fn * 16 + l15;
#pragma unroll
      for (int kk = 0; kk < 2; ++kk)
        bfr[fn][kk] = *reinterpret_cast<const bf16x8*>(
            (const char*)Bb + R * 128 + (((kk * 4 + hi) ^ (R & 7)) * 16));
    }
  }
  if (doSt) {
#pragma unroll
    for (int s = 0; s < NS; ++s)
      stg64(SP, sld, srow + s * 64, skt, sdst + s * 8192, tid);
  }
  __builtin_amdgcn_s_barrier();
  asm volatile("s_waitcnt lgkmcnt(0)" ::: "memory");
  __builtin_amdgcn_sched_barrier(0);
  __builtin_amdgcn_s_setprio(1);
#pragma unroll
  for (int kk = 0; kk < 2; ++kk)
#pragma unroll
    for (int fm = 0; fm < 2; ++fm)
#pragma unroll
      for (int fn = 0; fn < 2; ++fn)
        acc[QM * 2 + fm][QN * 2 + fn] = __builtin_amdgcn_mfma_f32_16x16x32_bf16(
            afr[fm][kk], bfr[fn][kk], acc[QM * 2 + fm][QN * 2 + fn], 0, 0, 0);
  __builtin_amdgcn_s_setprio(0);
  if constexpr (VW == 3) asm volatile("s_waitcnt vmcnt(3)" ::: "memory");
  if constexpr (VW == 0) asm volatile("s_waitcnt vmcnt(0)" ::: "memory");
  __builtin_amdgcn_s_barrier();
}

// Grid: 256 blocks; xcd = bid&7, lid = bid>>3; m = lid%16, n = xcd*2 + lid/16.
__global__ __launch_bounds__(512) void g2_8p(const __bf16* __restrict__ A,
                                             const __bf16* __restrict__ B,
                                             float* __restrict__ C, int K,
                                             int lda, int ldb, int ldc) {
  __shared__ __align__(16) __bf16 As[2][128 * 64];
  __shared__ __align__(16) __bf16 Bs[2][256 * 64];
  const int tid = threadIdx.x;
  const int l15 = tid & 15, hi = (tid >> 4) & 3, w = tid >> 6;
  const int wm = w >> 2, wn = w & 3;
  const int bid = blockIdx.x, xcd = bid & 7, lid = bid >> 3;
  const int m0 = (lid % 16) * 128;
  const int n0 = (xcd * 2 + lid / 16) * 256;

  f32x4 acc[4][4] = {};
  bf16x8 afr[2][2], bfr[2][2];
  char* A0 = (char*)As[0]; char* A1 = (char*)As[1];
  char* B0 = (char*)Bs[0]; char* B1 = (char*)Bs[1];

  // prologue (FIFO): t0 {A0(1),B0(2),A1(1),B1(2)} -> buf0 ; t1 {A0(1), B1(2)} -> buf1
  stg64(A, lda, m0,       0, A0,         tid);
  stg64(B, ldb, n0,       0, B0,         tid); stg64(B, ldb, n0 + 64,  0, B0 + 8192,  tid);
  stg64(A, lda, m0 + 64,  0, A0 + 8192,  tid);
  stg64(B, ldb, n0 + 128, 0, B0 + 16384, tid); stg64(B, ldb, n0 + 192, 0, B0 + 24576, tid);
  stg64(A, lda, m0,       1, A1,         tid);
  stg64(B, ldb, n0 + 128, 1, B1 + 16384, tid); stg64(B, ldb, n0 + 192, 1, B1 + 24576, tid);
  asm volatile("s_waitcnt vmcnt(3)" ::: "memory");   // t0 landed; t1 A0,B1 in flight
  __builtin_amdgcn_s_barrier();

  const int nt = K >> 6;
  for (int it = 0; it < nt; it += 2) {
    const bool sB = (it + 2 < nt), sC = (it + 3 < nt);
    const bool last = !sB;
    const __bf16* Ab0 = As[0]; const __bf16* Bb0 = Bs[0];
    const __bf16* Ab1 = As[1]; const __bf16* Bb1 = Bs[1];
    // phases 1-4: tile it (buf0)
    g2_phase<0, 0, true,  true, -1, 1>(Ab0, Bb0, acc, afr, bfr, wm, wn, l15, hi, tid,
                                       A, lda, m0 + 64, it + 1, A1 + 8192, true);  // t+1:A1
    g2_phase<0, 1, false, true, -1, 2>(Ab0, Bb0, acc, afr, bfr, wm, wn, l15, hi, tid,
                                       B, ldb, n0, it + 1, B1, true);              // t+1:B0
    g2_phase<1, 1, true, false, -1, 1>(Ab0, Bb0, acc, afr, bfr, wm, wn, l15, hi, tid,
                                       A, lda, m0, it + 2, A0, sB);                // t+2:A0
    if (last)
      g2_phase<1, 0, false, true, 0, 2>(Ab0, Bb0, acc, afr, bfr, wm, wn, l15, hi, tid,
                                        B, ldb, n0 + 128, it + 2, B0 + 16384, sB);
    else
      g2_phase<1, 0, false, true, 3, 2>(Ab0, Bb0, acc, afr, bfr, wm, wn, l15, hi, tid,
                                        B, ldb, n0 + 128, it + 2, B0 + 16384, sB); // t+2:B1
    // phases 5-8: tile it+1 (buf1)
    g2_phase<0, 0, true,  true, -1, 1>(Ab1, Bb1, acc, afr, bfr, wm, wn, l15, hi, tid,
                                       A, lda, m0 + 64, it + 2, A0 + 8192, sB);    // t+2:A1
    g2_phase<0, 1, false, true, -1, 2>(Ab1, Bb1, acc, afr, bfr, wm, wn, l15, hi, tid,
                                       B, ldb, n0, it + 2, B0, sB);                // t+2:B0
    g2_phase<1, 1, true, false, -1, 1>(Ab1, Bb1, acc, afr, bfr, wm, wn, l15, hi, tid,
                                       A, lda, m0, it + 3, A1, sC);                // t+3:A0
    if (last)
      g2_phase<1, 0, false, true, 0, 2>(Ab1, Bb1, acc, afr, bfr, wm, wn, l15, hi, tid,
                                        B, ldb, n0 + 128, it + 3, B1 + 16384, sC);
    else
      g2_phase<1, 0, false, true, 3, 2>(Ab1, Bb1, acc, afr, bfr, wm, wn, l15, hi, tid,
                                        B, ldb, n0 + 128, it + 3, B1 + 16384, sC); // t+3:B1
  }

  // epilogue
#pragma unroll
  for (int qm = 0; qm < 2; ++qm)
#pragma unroll
    for (int fm = 0; fm < 2; ++fm)
#pragma unroll
      for (int qn = 0; qn < 2; ++qn)
#pragma unroll
        for (int fn = 0; fn < 2; ++fn)
#pragma unroll
          for (int j = 0; j < 4; ++j) {
            int row = m0 + wm * 64 + qm * 32 + fm * 16 + hi * 4 + j;
            int col = n0 + wn * 64 + qn * 32 + fn * 16 + l15;
            C[(size_t)row * ldc + col] = acc[qm * 2 + fm][qn * 2 + fn][j];
          }
}

// ---------------- Flash attention, causal, GQA — staged K/V, 2 blocks/CU ---
// 512 blocks x 256 thr (4 waves x 32 q-rows, QBLK=128). Static-index V^T
// staging (stride 66), scale folded into exp2 fma, setprio around MFMA.
__device__ inline uint32_t pack2(float a, float b) {
  bf16x2 t; t[0] = (__bf16)a; t[1] = (__bf16)b;
  return __builtin_bit_cast(uint32_t, t);
}

__global__ __launch_bounds__(256, 2) void attn_kernel(const __bf16* __restrict__ qkv,
                                                      __bf16* __restrict__ out) {
  __shared__ __align__(16) __bf16 Ks[2][64 * 128];   // XOR-swizzled 16B groups
  __shared__ __align__(16) __bf16 Vt[2][128][66];    // V^T, stride 132B
  const int tid = threadIdx.x;
  const int lane = tid & 63, l31 = lane & 31, hi = lane >> 5, wq = tid >> 6;
  const int head = blockIdx.x & 31;
  const int g = blockIdx.x >> 5;                     // 0..15
  const int qt = (g < 8) ? (15 - g) : (g - 8);       // LPT + slot pairing
  const int q0 = qt * 128;
  const int nt = 2 * qt + 2;                         // kv tiles (causal)
  const int kvh = head >> 2;
  const float sc2 = 0.08838834764831845f * 1.44269504089f;  // 1/sqrt(128)*log2(e)
  const int qr = q0 + wq * 32 + l31;                 // this lane's q row

  bf16x8 vr[2][2];  // in-flight V rows (2 tasks x 2 rows)

  auto stage_k = [&](int tt, int buf) {
#pragma unroll
    for (int i = 0; i < 4; ++i) {
      int c = i * 256 + tid;                         // 16B chunk 0..1023
      int r = c >> 4, gg = c & 15;
      const __bf16* gk = qkv + (size_t)(tt * 64 + r) * QKV_LD + KOFF + kvh * HD + ((gg ^ (r & 7)) * 8);
      __builtin_amdgcn_global_load_lds((gaddr_t)gk,
          (laddr_t)((char*)Ks[buf] + (tid & ~63) * 16 + i * 4096), 16, 0, 0);
    }
  };
  auto load_v = [&](int tt) {
#pragma unroll
    for (int i = 0; i < 2; ++i) {
      int task = i * 256 + tid;                      // 0..511
      int p = task >> 4, cg = task & 15;
      const __bf16* vp = qkv + (size_t)(tt * 64 + 2 * p) * QKV_LD + VOFF + kvh * HD + cg * 8;
      vr[i][0] = *reinterpret_cast<const bf16x8*>(vp);
      vr[i][1] = *reinterpret_cast<const bf16x8*>(vp + QKV_LD);
    }
  };
  auto write_v = [&](int buf) {
#pragma unroll
    for (int i = 0; i < 2; ++i) {
      int task = i * 256 + tid;
      int p = task >> 4, cg = task & 15;
#pragma unroll
      for (int e = 0; e < 8; ++e) {                  // STATIC index — no select trees
        bf16x2 pkv; pkv[0] = vr[i][0][e]; pkv[1] = vr[i][1][e];
        *reinterpret_cast<bf16x2*>(&Vt[buf][cg * 8 + e][2 * p]) = pkv;
      }
    }
  };

  // Q fragments (B-layout): lane holds Q[qr][k = ks*16 + hi*8 + 0..7]
  bf16x8 qf[8];
  {
    const __bf16* qp = qkv + (size_t)qr * QKV_LD + head * HD + hi * 8;
#pragma unroll
    for (int ks = 0; ks < 8; ++ks) qf[ks] = *reinterpret_cast<const bf16x8*>(qp + ks * 16);
  }
  f32x16 o[4] = {};
  float m_run = -3e38f, l_run = 0.f;

  stage_k(0, 0); load_v(0); write_v(0);

  for (int t = 0; t < nt; ++t) {
    const int cur = t & 1;
    __syncthreads();        // staging of buf[cur] visible; prev reads of buf[1-cur] done
    if (t + 1 < nt) { stage_k(t + 1, 1 - cur); load_v(t + 1); }

    // ---- S^T = K Q^T : col=q=l31, row=(e&3)+8*(e>>2)+4*hi  (RAW scores)
    f32x16 st[2];
    __builtin_amdgcn_s_setprio(1);
#pragma unroll
    for (int sub = 0; sub < 2; ++sub) {
      f32x16 acc = {};
      int r = sub * 32 + l31;
#pragma unroll
      for (int ks = 0; ks < 8; ++ks) {
        int gg = (ks * 2 + hi) ^ (r & 7);
        bf16x8 kf = *reinterpret_cast<const bf16x8*>((char*)Ks[cur] + r * 256 + gg * 16);
        acc = __builtin_amdgcn_mfma_f32_32x32x16_bf16(kf, qf[ks], acc, 0, 0, 0);
      }
      st[sub] = acc;
    }
    __builtin_amdgcn_s_setprio(0);
    if (t >= nt - 2) {      // only the two diagonal tiles need masking
      const int kv0 = t * 64;
#pragma unroll
      for (int sub = 0; sub < 2; ++sub)
#pragma unroll
        for (int e = 0; e < 16; ++e) {
          int kvg = kv0 + sub * 32 + (e & 3) + 8 * (e >> 2) + 4 * hi;
          if (kvg > qr) st[sub][e] = -1e30f;
        }
    }
    // ---- online softmax (lane-local, defer-max, scale folded into exp2 fma)
    float pm = st[0][0];
#pragma unroll
    for (int e = 1; e < 16; ++e) pm = fmaxf(pm, st[0][e]);
#pragma unroll
    for (int e = 0; e < 16; ++e) pm = fmaxf(pm, st[1][e]);
    pm = fmaxf(pm, __shfl_xor(pm, 32));
    pm *= sc2;                                       // to scaled domain
    if (!__all(pm - m_run <= 8.f)) {
      float mn = fmaxf(m_run, pm);
      float fsc = EXP2F(m_run - mn);
      m_run = mn;
      l_run *= fsc;
#pragma unroll
      for (int dt = 0; dt < 4; ++dt)
#pragma unroll
        for (int e = 0; e < 16; ++e) o[dt][e] *= fsc;
    }
    float rs = 0.f;
#pragma unroll
    for (int sub = 0; sub < 2; ++sub)
#pragma unroll
      for (int e = 0; e < 16; ++e) {
        float p = EXP2F(__builtin_fmaf(st[sub][e], sc2, -m_run));
        st[sub][e] = p;
        rs += p;
      }
    rs += __shfl_xor(rs, 32);
    l_run += rs;

    // ---- pack P to bf16 B-fragments: pf[tt] = P[qr][kv = tt*16 + hi*8 + 0..7]
    uint32_t pk[16];
#pragma unroll
    for (int sub = 0; sub < 2; ++sub)
#pragma unroll
      for (int i = 0; i < 8; ++i)
        pk[sub * 8 + i] = pack2(st[sub][2 * i], st[sub][2 * i + 1]);
    uint32_t rv[8];
#pragma unroll
    for (int m = 0; m < 8; ++m) {
      int base = 4 * (m >> 1) + (m & 1);
      uint32_t snd = hi ? pk[base] : pk[base + 2];
      rv[m] = __shfl_xor(snd, 32);
    }
    bf16x8 pf[4];
#pragma unroll
    for (int tt = 0; tt < 4; ++tt) {
      u32x4 wv;
      wv[0] = hi ? rv[2 * tt]     : pk[4 * tt];
      wv[1] = hi ? rv[2 * tt + 1] : pk[4 * tt + 1];
      wv[2] = hi ? pk[4 * tt + 2] : rv[2 * tt];
      wv[3] = hi ? pk[4 * tt + 3] : rv[2 * tt + 1];
      pf[tt] = __builtin_bit_cast(bf16x8, wv);
    }
    // ---- O^T += V^T P^T
    __builtin_amdgcn_s_setprio(1);
#pragma unroll
    for (int dt = 0; dt < 4; ++dt) {
      int dr = dt * 32 + l31;
#pragma unroll
      for (int tt = 0; tt < 4; ++tt) {
        bf16x8 vf = *reinterpret_cast<const bf16x8*>((char*)&Vt[cur][0][0] + dr * 132 + tt * 32 + hi * 16);
        o[dt] = __builtin_amdgcn_mfma_f32_32x32x16_bf16(vf, pf[tt], o[dt], 0, 0, 0);
      }
    }
    __builtin_amdgcn_s_setprio(0);
    // ---- late V^T write for next tile (loads had QK+softmax+PV to land)
    if (t + 1 < nt) write_v(1 - cur);
  }

  // ---- epilogue: transpose O^T -> O via per-wave LDS scratch, coalesced stores
  float inv = 1.f / l_run;
  __bf16* scr = &Ks[0][0] + wq * 1280;               // [32][40] bf16 per wave
  const int qq = lane >> 1, part = lane & 1;
#pragma unroll
  for (int dt = 0; dt < 4; ++dt) {
    __syncthreads();                                 // all waves done reading Ks/Vt (or prev dt)
#pragma unroll
    for (int i = 0; i < 8; ++i) {
      int d0 = (2 * i & 3) + 8 * (i >> 1) + 4 * hi;
      bf16x2 prr;
      prr[0] = (__bf16)(o[dt][2 * i] * inv);
      prr[1] = (__bf16)(o[dt][2 * i + 1] * inv);
      *reinterpret_cast<bf16x2*>(scr + l31 * 40 + d0) = prr;
    }
    __syncthreads();
    bf16x8 r0 = *reinterpret_cast<const bf16x8*>(scr + qq * 40 + part * 16);
    bf16x8 r1 = *reinterpret_cast<const bf16x8*>(scr + qq * 40 + part * 16 + 8);
    __bf16* op = out + (size_t)(q0 + wq * 32 + qq) * DIM_ + head * HD + dt * 32 + part * 16;
    *reinterpret_cast<bf16x8*>(op) = r0;
    *reinterpret_cast<bf16x8*>(op + 8) = r1;
  }
}

// ---------------------------------------------------------------------------
extern "C" void kernel_launch(void* const* d_in, const int* in_sizes, int n_in,
                              void* d_out, int out_size, void* d_ws, size_t ws_size,
                              hipStream_t stream) {
  (void)in_sizes; (void)n_in; (void)out_size; (void)ws_size;
  const float* x    = (const float*)d_in[0];
  const float* fc   = (const float*)d_in[1];
  const float* fs   = (const float*)d_in[2];
  // d_in[3] = mask (causal, hardcoded in attn_kernel)
  const float* wqkv = (const float*)d_in[4];
  const float* wo   = (const float*)d_in[5];
  float* out = (float*)d_out;

  char* ws = (char*)d_ws;
  __bf16* xb    = (__bf16*)(ws);                       // 16,777,216  (reused as attn_out)
  __bf16* wqkvb = (__bf16*)(ws + 16777216);            // 50,331,648
  __bf16* wob   = (__bf16*)(ws + 67108864);            // 33,554,432
  __bf16* qkv   = (__bf16*)(ws + 100663296);           // 25,165,824
  __bf16* attnO = xb;                                  // xb dead after gemm1

  // single fused conversion pass (x, wqkv, wo)
  cvt3<<<2048, 256, 0, stream>>>(x, xb, wqkv, wqkvb, wo, wob);

  // qkv = x @ wqkv^T : 128x384 tiles, 16x16 = 256 blocks (100% CU), 8-phase.
  g1_8p<<<256, 512, 0, stream>>>(xb, wqkvb, qkv, DIM_, DIM_, DIM_, QKV_LD);

  // rope on Q + K parts (standalone — cheaper than epilogue fusion, R17)
  rope_kernel<<<(S_LEN * 40 * 64) / 256, 256, 0, stream>>>(qkv, fc, fs);

  // causal GQA attention (512 blocks x 256 threads, 2 blocks/CU, paired LPT)
  attn_kernel<<<512, 256, 0, stream>>>(qkv, attnO);

  // out = attnO @ wo^T : 128x256 tiles, 256 blocks, 8-phase (g1 mirror).
  g2_8p<<<256, 512, 0, stream>>>(attnO, wob, out, DIM_, DIM_, DIM_, DIM_);
}